// Round 11
// baseline (320.062 us; speedup 1.0000x reference)
//
#include <hip/hip_runtime.h>

// ---------------------------------------------------------------------------
// GNNStack — dead-code-eliminated (edge-update MLPs never reach the output).
// Matmuls on MFMA bf16, split precision where it matters:
//   X (node features): interleaved [node][hi 128 | lo 128] bf16 (512 B row)
//   B (aggregated mean): dense bf16 (256 B row) — inputs already bf16.
//   C = Ahi*Bhi (+ Alo*Bhi if A has lo) + Ahi*Blo, fp32 AGPR accum.
// GEMM: swapped MFMA operands (packed uint2 epilogue stores), 4-wave blocks,
// 128 rows/block. A fragments preloaded to registers BEFORE weight staging;
// weights staged via async global_load_lds width=16 (no VGPR round-trip).
// ---------------------------------------------------------------------------

typedef __attribute__((ext_vector_type(8))) short bf16x8;
typedef __attribute__((ext_vector_type(4))) float f32x4;

__device__ __forceinline__ unsigned short f2bf(float x) {
  unsigned u = __float_as_uint(x);
  u += 0x7fffu + ((u >> 16) & 1u);
  return (unsigned short)(u >> 16);
}
__device__ __forceinline__ float bf2f(unsigned short h) {
  return __uint_as_float(((unsigned)h) << 16);
}
__device__ __forceinline__ float lo16f(unsigned u) { return __uint_as_float(u << 16); }
__device__ __forceinline__ float hi16f(unsigned u) { return __uint_as_float(u & 0xffff0000u); }

// async global -> LDS, 16 bytes per lane (wave-uniform base + lane*16 pattern)
__device__ __forceinline__ void gload_lds16(const void* g, void* l) {
  __builtin_amdgcn_global_load_lds(
      (const __attribute__((address_space(1))) unsigned int*)g,
      (__attribute__((address_space(3))) unsigned int*)l, 16, 0, 0);
}

// ---------------- CSR build ----------------
__global__ void k_count(const int* __restrict__ dst, int* __restrict__ cnt, int E) {
  int i = blockIdx.x * blockDim.x + threadIdx.x;
  if (i < E) atomicAdd(&cnt[dst[i]], 1);
}

__global__ void k_scan1(const int* __restrict__ cnt, int* __restrict__ rs,
                        float* __restrict__ degf, int* __restrict__ bsum, int n) {
  __shared__ int wsum[16];
  __shared__ int wpre[16];
  const int tid = threadIdx.x;
  const int lane = tid & 63;
  const int wv = tid >> 6;
  int i = blockIdx.x * 1024 + tid;
  int v = (i < n) ? cnt[i] : 0;
  int s = v;
#pragma unroll
  for (int off = 1; off < 64; off <<= 1) {
    int t = __shfl_up(s, off);
    if (lane >= off) s += t;
  }
  if (lane == 63) wsum[wv] = s;
  __syncthreads();
  if (tid < 16) {
    int t = wsum[tid];
    int ss = t;
#pragma unroll
    for (int off = 1; off < 16; off <<= 1) {
      int u = __shfl_up(ss, off);
      if (tid >= off) ss += u;
    }
    wpre[tid] = ss - t;
  }
  __syncthreads();
  if (i < n) {
    rs[i] = s - v + wpre[wv];
    degf[i] = (float)(v > 0 ? v : 1);
  }
  if (tid == 1023) bsum[blockIdx.x] = wpre[15] + wsum[15];
}

// scan of block sums folded in: wave 0 of every block redundantly scans bsum
__global__ void k_scan3(int* __restrict__ rs, const int* __restrict__ bsum,
                        int* __restrict__ cursor, int n, int nb) {
  __shared__ int boff_s[64];
  __shared__ int total_s;
  int tid = threadIdx.x;
  if (tid < 64) {
    int v = (tid < nb) ? bsum[tid] : 0;
    int s = v;
#pragma unroll
    for (int off = 1; off < 64; off <<= 1) {
      int t = __shfl_up(s, off);
      if (tid >= off) s += t;
    }
    boff_s[tid] = s - v;
    if (tid == 63) total_s = s;
  }
  __syncthreads();
  int i = blockIdx.x * blockDim.x + tid;
  if (i < n) {
    int r = rs[i] + boff_s[i >> 10];
    rs[i] = r;
    cursor[i] = r;
  }
  if (blockIdx.x == 0 && tid == 0) rs[n] = total_s;
}

__global__ void k_scatter(const int* __restrict__ src, const int* __restrict__ dst,
                          int* __restrict__ cursor, int* __restrict__ csr, int E) {
  int i = blockIdx.x * blockDim.x + threadIdx.x;
  if (i < E) {
    int p = atomicAdd(&cursor[dst[i]], 1);
    csr[p] = src[i];
  }
}

// ---------------- fp32 -> interleaved hi|lo X row ----------------
__global__ void k_split(const float* __restrict__ x, unsigned* __restrict__ X,
                        long n2) {
  long g = (long)blockIdx.x * blockDim.x + threadIdx.x;
  if (g >= n2) return;
  float2 v = ((const float2*)x)[g];
  unsigned short hx = f2bf(v.x), hy = f2bf(v.y);
  unsigned short lx = f2bf(v.x - bf2f(hx)), ly = f2bf(v.y - bf2f(hy));
  long row = g >> 6, p = g & 63;
  X[row * 128 + p] = (unsigned)hx | ((unsigned)hy << 16);
  X[row * 128 + 64 + p] = (unsigned)lx | ((unsigned)ly << 16);
}

// ---------------- all weights pack: frag-order bf16 hi/lo, 10 mats ----------
// frag f = nt*4 + ks; lane l supplies B[k0 + 8*(l>>4) + r][nt*16 + (l&15)]
__global__ void k_packAll(const float* __restrict__ Wl, const float* __restrict__ Wr,
                          const float* __restrict__ pW1, const float* __restrict__ pW2,
                          const float* __restrict__ qW1,
                          unsigned short* __restrict__ hi,
                          unsigned short* __restrict__ lo) {
  int gid = blockIdx.x * blockDim.x + threadIdx.x;
  if (gid >= 10 * 2048) return;
  int mat = gid >> 11;
  const float* Wm;
  if (mat < 3) Wm = Wl + (size_t)mat * 16384;
  else if (mat < 6) Wm = Wr + (size_t)(mat - 3) * 16384;
  else if (mat == 6) Wm = pW1;
  else if (mat == 7) Wm = pW2;
  else Wm = qW1 + (size_t)(mat - 8) * 16384;
  int lane = gid & 63;
  int f = (gid >> 6) & 31;
  int nt = f >> 2, ks = f & 3;
  int nn = nt * 16 + (lane & 15);
  int k0 = ks * 32 + 8 * (lane >> 4);
  size_t dst = (size_t)gid * 8;
#pragma unroll
  for (int r = 0; r < 8; ++r) {
    float w = Wm[(size_t)(k0 + r) * 128 + nn];
    unsigned short h = f2bf(w);
    hi[dst + r] = h;
    lo[dst + r] = f2bf(w - bf2f(h));
  }
}

// biasuv = [qb1 | zeros(128)]
__global__ void k_biasuv(const float* __restrict__ qb1, float* __restrict__ b) {
  int i = threadIdx.x;  // 256
  b[i] = (i < 128) ? qb1[i] : 0.f;
}

// ---------------- mean aggregation over X hi-halves -> dense bf16 B ---------
__global__ void k_aggr(const unsigned short* __restrict__ X,
                       const int* __restrict__ csr, const int* __restrict__ rs,
                       const float* __restrict__ degf,
                       unsigned short* __restrict__ Bd, int n) {
  int gid = blockIdx.x * blockDim.x + threadIdx.x;
  int wid = gid >> 6, lane = gid & 63;
  if (wid >= n) return;
  int s = rs[wid], e = rs[wid + 1];
  const int h = lane >> 4;         // neighbor slot (0..3)
  const int o16 = (lane & 15) * 8; // ushort offset within 256 B hi half
  float a0 = 0.f, a1 = 0.f, a2 = 0.f, a3 = 0.f;
  float a4 = 0.f, a5 = 0.f, a6 = 0.f, a7 = 0.f;
  int j = s;
  for (; j + 7 < e; j += 8) {
    int n0 = csr[j + h];
    int n1 = csr[j + 4 + h];
    uint4 v0 = *(const uint4*)(X + (size_t)n0 * 256 + o16);
    uint4 v1 = *(const uint4*)(X + (size_t)n1 * 256 + o16);
    a0 += lo16f(v0.x) + lo16f(v1.x);
    a1 += hi16f(v0.x) + hi16f(v1.x);
    a2 += lo16f(v0.y) + lo16f(v1.y);
    a3 += hi16f(v0.y) + hi16f(v1.y);
    a4 += lo16f(v0.z) + lo16f(v1.z);
    a5 += hi16f(v0.z) + hi16f(v1.z);
    a6 += lo16f(v0.w) + lo16f(v1.w);
    a7 += hi16f(v0.w) + hi16f(v1.w);
  }
  for (; j < e; j += 4) {
    int idx = j + h;
    bool ok = idx < e;
    int nn = ok ? csr[idx] : 0;
    uint4 v = *(const uint4*)(X + (size_t)nn * 256 + o16);
    float m = ok ? 1.f : 0.f;
    a0 += m * lo16f(v.x); a1 += m * hi16f(v.x);
    a2 += m * lo16f(v.y); a3 += m * hi16f(v.y);
    a4 += m * lo16f(v.z); a5 += m * hi16f(v.z);
    a6 += m * lo16f(v.w); a7 += m * hi16f(v.w);
  }
  a0 += __shfl_xor(a0, 16); a1 += __shfl_xor(a1, 16);
  a2 += __shfl_xor(a2, 16); a3 += __shfl_xor(a3, 16);
  a4 += __shfl_xor(a4, 16); a5 += __shfl_xor(a5, 16);
  a6 += __shfl_xor(a6, 16); a7 += __shfl_xor(a7, 16);
  a0 += __shfl_xor(a0, 32); a1 += __shfl_xor(a1, 32);
  a2 += __shfl_xor(a2, 32); a3 += __shfl_xor(a3, 32);
  a4 += __shfl_xor(a4, 32); a5 += __shfl_xor(a5, 32);
  a6 += __shfl_xor(a6, 32); a7 += __shfl_xor(a7, 32);
  if (lane < 16) {
    float inv = 1.0f / degf[wid];
    unsigned short h0 = f2bf(a0 * inv), h1 = f2bf(a1 * inv);
    unsigned short h2 = f2bf(a2 * inv), h3 = f2bf(a3 * inv);
    unsigned short h4 = f2bf(a4 * inv), h5 = f2bf(a5 * inv);
    unsigned short h6 = f2bf(a6 * inv), h7 = f2bf(a7 * inv);
    uint4 oh;
    oh.x = (unsigned)h0 | ((unsigned)h1 << 16);
    oh.y = (unsigned)h2 | ((unsigned)h3 << 16);
    oh.z = (unsigned)h4 | ((unsigned)h5 << 16);
    oh.w = (unsigned)h6 | ((unsigned)h7 << 16);
    *(uint4*)(Bd + (size_t)wid * 128 + o16) = oh;
  }
}

// ---------------- MFMA GEMM: preloaded A regs + async LDS weight staging ----
// 256 threads = 4 waves; each wave owns 32 rows; 128 rows/block. NT=8,
// LDS 64 KiB -> 2 resident blocks/CU. mfma(w_frag, x_frag): lane owns a col
// quad -> packed uint2 epilogue stores.
// A0DENSE: phase-0 A is dense bf16 (stride 128, no lo, 2 MFMAs/frag).
// EPI: 0 = relu + interleaved out; 1 = interleaved out; 2 = dense bf16 out.
template <int NPHASE, int EPI, int A0DENSE>
__global__ __launch_bounds__(256) void k_gemm(
    const unsigned short* __restrict__ A0, const unsigned short* __restrict__ A1,
    const unsigned short* __restrict__ W0h, const unsigned short* __restrict__ W0l,
    const unsigned short* __restrict__ W1h, const unsigned short* __restrict__ W1l,
    const float* __restrict__ bias, unsigned short* __restrict__ O, int nrows) {
  __shared__ unsigned short smem[8 * 4096];  // hi: 16384, lo: 16384 ushorts
  unsigned short* smh = smem;
  unsigned short* sml = smem + 8 * 2048;

  const int tid = threadIdx.x;
  const int lane = tid & 63;
  const int wv = tid >> 6;  // 0..3
  const long row0 = ((long)blockIdx.x * 4 + wv) * 32;
  const bool active = row0 < nrows;
  const int kgrp = (lane >> 4) * 8;

  long arow[2];
#pragma unroll
  for (int rs = 0; rs < 2; ++rs) {
    long r = row0 + rs * 16 + (lane & 15);
    arow[rs] = (r < nrows) ? r : (long)(nrows - 1);
  }

  // issue phase-0 weight staging (async, direct to LDS)
#pragma unroll
  for (int k = 0; k < 8; ++k) {
    int t = tid + k * 256;
    gload_lds16((const uint4*)W0h + t, (uint4*)smh + t);
    gload_lds16((const uint4*)W0l + t, (uint4*)sml + t);
  }

  // preload ALL A fragments into registers (overlaps with weight staging)
  bf16x8 a0h[2][4], a0l[2][4], a1h[2][4], a1l[2][4];
  if (active) {
#pragma unroll
    for (int rs = 0; rs < 2; ++rs)
#pragma unroll
      for (int ks = 0; ks < 4; ++ks) {
        if (A0DENSE) {
          a0h[rs][ks] = *(const bf16x8*)(A0 + arow[rs] * 128 + ks * 32 + kgrp);
        } else {
          a0h[rs][ks] = *(const bf16x8*)(A0 + arow[rs] * 256 + ks * 32 + kgrp);
          a0l[rs][ks] = *(const bf16x8*)(A0 + arow[rs] * 256 + 128 + ks * 32 + kgrp);
        }
        if (NPHASE == 2) {
          a1h[rs][ks] = *(const bf16x8*)(A1 + arow[rs] * 256 + ks * 32 + kgrp);
          a1l[rs][ks] = *(const bf16x8*)(A1 + arow[rs] * 256 + 128 + ks * 32 + kgrp);
        }
      }
  }

  f32x4 zero = {0.f, 0.f, 0.f, 0.f};
  f32x4 acc[2][8];
#pragma unroll
  for (int rs = 0; rs < 2; ++rs)
#pragma unroll
    for (int t = 0; t < 8; ++t) acc[rs][t] = zero;

  __syncthreads();  // phase-0 weights in LDS, A regs ready

  if (active) {
#pragma unroll
    for (int ks = 0; ks < 4; ++ks) {
#pragma unroll
      for (int nt = 0; nt < 8; ++nt) {
        const bf16x8 b_h = *(const bf16x8*)(smh + (nt * 4 + ks) * 512 + lane * 8);
        const bf16x8 b_l = *(const bf16x8*)(sml + (nt * 4 + ks) * 512 + lane * 8);
#pragma unroll
        for (int rs = 0; rs < 2; ++rs) {
          acc[rs][nt] = __builtin_amdgcn_mfma_f32_16x16x32_bf16(b_h, a0h[rs][ks], acc[rs][nt], 0, 0, 0);
          if (!A0DENSE)
            acc[rs][nt] = __builtin_amdgcn_mfma_f32_16x16x32_bf16(b_h, a0l[rs][ks], acc[rs][nt], 0, 0, 0);
          acc[rs][nt] = __builtin_amdgcn_mfma_f32_16x16x32_bf16(b_l, a0h[rs][ks], acc[rs][nt], 0, 0, 0);
        }
      }
    }
  }

  if (NPHASE == 2) {
    __syncthreads();  // all waves done reading phase-0 LDS
#pragma unroll
    for (int k = 0; k < 8; ++k) {
      int t = tid + k * 256;
      gload_lds16((const uint4*)W1h + t, (uint4*)smh + t);
      gload_lds16((const uint4*)W1l + t, (uint4*)sml + t);
    }
    __syncthreads();
    if (active) {
#pragma unroll
      for (int ks = 0; ks < 4; ++ks) {
#pragma unroll
        for (int nt = 0; nt < 8; ++nt) {
          const bf16x8 b_h = *(const bf16x8*)(smh + (nt * 4 + ks) * 512 + lane * 8);
          const bf16x8 b_l = *(const bf16x8*)(sml + (nt * 4 + ks) * 512 + lane * 8);
#pragma unroll
          for (int rs = 0; rs < 2; ++rs) {
            acc[rs][nt] = __builtin_amdgcn_mfma_f32_16x16x32_bf16(b_h, a1h[rs][ks], acc[rs][nt], 0, 0, 0);
            acc[rs][nt] = __builtin_amdgcn_mfma_f32_16x16x32_bf16(b_h, a1l[rs][ks], acc[rs][nt], 0, 0, 0);
            acc[rs][nt] = __builtin_amdgcn_mfma_f32_16x16x32_bf16(b_l, a1h[rs][ks], acc[rs][nt], 0, 0, 0);
          }
        }
      }
    }
  }
  if (!active) return;

  const int cq = (lane >> 4) * 4;  // col quad base within 16-col tile
#pragma unroll
  for (int rs = 0; rs < 2; ++rs) {
    const long row = row0 + rs * 16 + (lane & 15);
    if (row >= nrows) continue;
#pragma unroll
    for (int nt = 0; nt < 8; ++nt) {
      const int col = nt * 16 + cq;
      float4 bv = *(const float4*)(bias + col);
      float v0 = acc[rs][nt][0] + bv.x;
      float v1 = acc[rs][nt][1] + bv.y;
      float v2 = acc[rs][nt][2] + bv.z;
      float v3 = acc[rs][nt][3] + bv.w;
      if (EPI == 0) {
        v0 = fmaxf(v0, 0.f); v1 = fmaxf(v1, 0.f);
        v2 = fmaxf(v2, 0.f); v3 = fmaxf(v3, 0.f);
      }
      unsigned short h0 = f2bf(v0), h1 = f2bf(v1), h2 = f2bf(v2), h3 = f2bf(v3);
      uint2 oh;
      oh.x = (unsigned)h0 | ((unsigned)h1 << 16);
      oh.y = (unsigned)h2 | ((unsigned)h3 << 16);
      if (EPI == 2) {
        *(uint2*)(O + row * 128 + col) = oh;
      } else {
        uint2 ol;
        ol.x = (unsigned)f2bf(v0 - bf2f(h0)) | ((unsigned)f2bf(v1 - bf2f(h1)) << 16);
        ol.y = (unsigned)f2bf(v2 - bf2f(h2)) | ((unsigned)f2bf(v3 - bf2f(h3)) << 16);
        *(uint2*)(O + row * 256 + col) = oh;
        *(uint2*)(O + row * 256 + 128 + col) = ol;
      }
    }
  }
}

// ---------------- predict pair: y = relu(u[i]+v[j]) . qW2 + qb2 -------------
__global__ __launch_bounds__(256) void k_pair(
    const unsigned short* __restrict__ u, const unsigned short* __restrict__ v,
    const int* __restrict__ ps, const int* __restrict__ pd,
    const float* __restrict__ qW2, const float* __restrict__ qb2,
    float* __restrict__ out, int EP) {
  int gid = blockIdx.x * blockDim.x + threadIdx.x;
  long wid = gid >> 6;
  int lane = gid & 63;
  int sub = lane & 15, g = lane >> 4;
  long base = wid * 8;
  if (base >= EP) return;
  float4 q0 = *(const float4*)(qW2 + sub * 8);
  float4 q1 = *(const float4*)(qW2 + sub * 8 + 4);
  float qb = qb2[0];

  long p0 = base + g;
  long p1 = base + 4 + g;
  long c0 = (p0 < EP) ? p0 : (EP - 1);
  long c1 = (p1 < EP) ? p1 : (EP - 1);
  int i0 = ps[c0], j0 = pd[c0];
  int i1 = ps[c1], j1 = pd[c1];
  uint4 a0 = *(const uint4*)(u + (size_t)i0 * 128 + sub * 8);
  uint4 b0 = *(const uint4*)(v + (size_t)j0 * 128 + sub * 8);
  uint4 a1 = *(const uint4*)(u + (size_t)i1 * 128 + sub * 8);
  uint4 b1 = *(const uint4*)(v + (size_t)j1 * 128 + sub * 8);

  float s0, s1;
  {
    float t;
    t = fmaxf(lo16f(a0.x) + lo16f(b0.x), 0.f) * q0.x;
    t = fmaf(fmaxf(hi16f(a0.x) + hi16f(b0.x), 0.f), q0.y, t);
    t = fmaf(fmaxf(lo16f(a0.y) + lo16f(b0.y), 0.f), q0.z, t);
    t = fmaf(fmaxf(hi16f(a0.y) + hi16f(b0.y), 0.f), q0.w, t);
    t = fmaf(fmaxf(lo16f(a0.z) + lo16f(b0.z), 0.f), q1.x, t);
    t = fmaf(fmaxf(hi16f(a0.z) + hi16f(b0.z), 0.f), q1.y, t);
    t = fmaf(fmaxf(lo16f(a0.w) + lo16f(b0.w), 0.f), q1.z, t);
    t = fmaf(fmaxf(hi16f(a0.w) + hi16f(b0.w), 0.f), q1.w, t);
    s0 = t;
    t = fmaxf(lo16f(a1.x) + lo16f(b1.x), 0.f) * q0.x;
    t = fmaf(fmaxf(hi16f(a1.x) + hi16f(b1.x), 0.f), q0.y, t);
    t = fmaf(fmaxf(lo16f(a1.y) + lo16f(b1.y), 0.f), q0.z, t);
    t = fmaf(fmaxf(hi16f(a1.y) + hi16f(b1.y), 0.f), q0.w, t);
    t = fmaf(fmaxf(lo16f(a1.z) + lo16f(b1.z), 0.f), q1.x, t);
    t = fmaf(fmaxf(hi16f(a1.z) + hi16f(b1.z), 0.f), q1.y, t);
    t = fmaf(fmaxf(lo16f(a1.w) + lo16f(b1.w), 0.f), q1.z, t);
    t = fmaf(fmaxf(hi16f(a1.w) + hi16f(b1.w), 0.f), q1.w, t);
    s1 = t;
  }
#pragma unroll
  for (int m = 1; m < 16; m <<= 1) {
    s0 += __shfl_xor(s0, m);
    s1 += __shfl_xor(s1, m);
  }
  if (sub == 0) {
    if (p0 < EP) out[p0] = s0 + qb;
    if (p1 < EP) out[p1] = s1 + qb;
  }
}

extern "C" void kernel_launch(void* const* d_in, const int* in_sizes, int n_in,
                              void* d_out, int out_size, void* d_ws, size_t ws_size,
                              hipStream_t stream) {
  const float* x_in = (const float*)d_in[0];
  // d_in[1] edge_attr: dead
  const int* ei = (const int*)d_in[2];
  const int* pe = (const int*)d_in[3];
  const float* Wl = (const float*)d_in[4];
  const float* bl = (const float*)d_in[5];
  const float* Wr = (const float*)d_in[6];
  // d_in[7..10] edge-update weights: dead
  const float* pW1 = (const float*)d_in[11];
  const float* pb1 = (const float*)d_in[12];
  const float* pW2 = (const float*)d_in[13];
  const float* pb2 = (const float*)d_in[14];
  const float* qW1 = (const float*)d_in[15];
  const float* qb1 = (const float*)d_in[16];
  const float* qW2 = (const float*)d_in[17];
  const float* qb2 = (const float*)d_in[18];

  const int N = in_sizes[0] / 128;
  const int E = in_sizes[2] / 2;
  const int EP = in_sizes[3] / 2;
  const int* e_src = ei;
  const int* e_dst = ei + E;
  const int* p_src = pe;
  const int* p_dst = pe + EP;

  char* ws = (char*)d_ws;
  size_t off = 0;
  auto alloc = [&](size_t bytes) {
    void* p = ws + off;
    off += (bytes + 511) & ~(size_t)511;
    return p;
  };
  // X: interleaved [node][hi|lo] (512 B rows). B: scratch — dense bf16
  // aggregated mean, then interleaved h1, then u|v.
  unsigned short* X = (unsigned short*)alloc((size_t)N * 256 * 2);  // 25.6 MB
  unsigned short* B = (unsigned short*)alloc((size_t)N * 256 * 2);  // 25.6 MB
  int* deg_i = (int*)alloc((size_t)N * 4);
  int* rs = (int*)alloc((size_t)(N + 1) * 4);
  int* cursor = (int*)alloc((size_t)N * 4);
  float* degf = (float*)alloc((size_t)N * 4);
  int* csr = (int*)alloc((size_t)E * 4);
  int* bsum = (int*)alloc(64 * 4);
  unsigned short* Whi = (unsigned short*)alloc((size_t)10 * 16384 * 2);
  unsigned short* Wlo = (unsigned short*)alloc((size_t)10 * 16384 * 2);
  float* biasuv = (float*)alloc(256 * 4);

  const size_t MS = 16384;  // mat stride in ushorts
  const int nb = (N + 1023) / 1024;

  hipMemsetAsync(deg_i, 0, (size_t)N * 4, stream);
  k_biasuv<<<1, 256, 0, stream>>>(qb1, biasuv);

  // pack all 10 weight mats (frag order, hi/lo split); mats 8,9 = qW1 t/b
  k_packAll<<<(10 * 2048 + 255) / 256, 256, 0, stream>>>(Wl, Wr, pW1, pW2, qW1,
                                                         Whi, Wlo);

  // x -> interleaved hi|lo
  long n2 = (long)N * 64;
  k_split<<<(int)((n2 + 255) / 256), 256, 0, stream>>>(x_in, (unsigned*)X, n2);

  // CSR (hierarchical scan; block-sum scan folded into scan3)
  k_count<<<(E + 255) / 256, 256, 0, stream>>>(e_dst, deg_i, E);
  k_scan1<<<nb, 1024, 0, stream>>>(deg_i, rs, degf, bsum, N);
  k_scan3<<<(N + 255) / 256, 256, 0, stream>>>(rs, bsum, cursor, N, nb);
  k_scatter<<<(E + 255) / 256, 256, 0, stream>>>(e_src, e_dst, cursor, csr, E);

  const int gmm = (N + 127) / 128;  // 128 rows/block, 4 waves
  const int agblocks = (N + 3) / 4;
  for (int l = 0; l < 3; ++l) {
    k_aggr<<<agblocks, 256, 0, stream>>>(X, csr, rs, degf, B, N);
    // x = relu(aggr@Wl + x@Wr + bl) -> X interleaved; aggr (B) is dense bf16
    // (in-place safe: rows wave-owned; A preloads precede epilogue stores)
    k_gemm<2, 0, 1><<<gmm, 256, 0, stream>>>(
        B, X, Whi + (size_t)l * MS, Wlo + (size_t)l * MS,
        Whi + (size_t)(3 + l) * MS, Wlo + (size_t)(3 + l) * MS,
        bl + (size_t)l * 128, X, N);
  }
  // h1 = relu(x@pW1+pb1) -> B (interleaved)
  k_gemm<1, 0, 0><<<gmm, 256, 0, stream>>>(
      X, nullptr, Whi + 6 * MS, Wlo + 6 * MS, nullptr, nullptr, pb1, B, N);
  // x2 = h1@pW2+pb2 -> X (in-place over x; B is the source)
  k_gemm<1, 1, 0><<<gmm, 256, 0, stream>>>(
      B, nullptr, Whi + 7 * MS, Wlo + 7 * MS, nullptr, nullptr, pb2, X, N);
  // u = x2@qW1t + qb1 ; v = x2@qW1b  (two NT=8 dispatches, 64 KiB LDS each)
  unsigned short* u = B;
  unsigned short* v = B + (size_t)N * 128;
  k_gemm<1, 2, 0><<<gmm, 256, 0, stream>>>(
      X, nullptr, Whi + 8 * MS, Wlo + 8 * MS, nullptr, nullptr, biasuv, u, N);
  k_gemm<1, 2, 0><<<gmm, 256, 0, stream>>>(
      X, nullptr, Whi + 9 * MS, Wlo + 9 * MS, nullptr, nullptr, biasuv + 128, v, N);
  // y = relu(u[i]+v[j]) . qW2 + qb2
  k_pair<<<(EP + 31) / 32, 256, 0, stream>>>(u, v, p_src, p_dst, qW2, qb2,
                                             (float*)d_out, EP);
}

// Round 12
// 314.775 us; speedup vs baseline: 1.0168x; 1.0168x over previous
//
#include <hip/hip_runtime.h>

// ---------------------------------------------------------------------------
// GNNStack — dead-code-eliminated (edge-update MLPs never reach the output).
// Matmuls on MFMA bf16, split precision where it matters:
//   X (node features): interleaved [node][hi 128 | lo 128] bf16 (512 B row)
//   B (aggregated mean): dense bf16 (256 B row) — inputs already bf16.
//   C = Ahi*Bhi (+ Alo*Bhi if A has lo) + Ahi*Blo, fp32 AGPR accum.
// GEMM: swapped MFMA operands (packed uint2 epilogue stores), 8-wave blocks
// (512 thr), 16 rows/wave, 128 rows/block, 64 KiB LDS -> 2 blocks/CU =
// 16 waves/CU. Rationale: gemm is outstanding-miss limited (Little's law);
// 2x waves => 2x bytes in flight => 2x streaming throughput.
// ---------------------------------------------------------------------------

typedef __attribute__((ext_vector_type(8))) short bf16x8;
typedef __attribute__((ext_vector_type(4))) float f32x4;

__device__ __forceinline__ unsigned short f2bf(float x) {
  unsigned u = __float_as_uint(x);
  u += 0x7fffu + ((u >> 16) & 1u);
  return (unsigned short)(u >> 16);
}
__device__ __forceinline__ float bf2f(unsigned short h) {
  return __uint_as_float(((unsigned)h) << 16);
}
__device__ __forceinline__ float lo16f(unsigned u) { return __uint_as_float(u << 16); }
__device__ __forceinline__ float hi16f(unsigned u) { return __uint_as_float(u & 0xffff0000u); }

// async global -> LDS, 16 bytes per lane (wave-uniform base + lane*16 pattern)
__device__ __forceinline__ void gload_lds16(const void* g, void* l) {
  __builtin_amdgcn_global_load_lds(
      (const __attribute__((address_space(1))) unsigned int*)g,
      (__attribute__((address_space(3))) unsigned int*)l, 16, 0, 0);
}

// ---------------- CSR build ----------------
__global__ void k_count(const int* __restrict__ dst, int* __restrict__ cnt, int E) {
  int i = blockIdx.x * blockDim.x + threadIdx.x;
  if (i < E) atomicAdd(&cnt[dst[i]], 1);
}

__global__ void k_scan1(const int* __restrict__ cnt, int* __restrict__ rs,
                        float* __restrict__ degf, int* __restrict__ bsum, int n) {
  __shared__ int wsum[16];
  __shared__ int wpre[16];
  const int tid = threadIdx.x;
  const int lane = tid & 63;
  const int wv = tid >> 6;
  int i = blockIdx.x * 1024 + tid;
  int v = (i < n) ? cnt[i] : 0;
  int s = v;
#pragma unroll
  for (int off = 1; off < 64; off <<= 1) {
    int t = __shfl_up(s, off);
    if (lane >= off) s += t;
  }
  if (lane == 63) wsum[wv] = s;
  __syncthreads();
  if (tid < 16) {
    int t = wsum[tid];
    int ss = t;
#pragma unroll
    for (int off = 1; off < 16; off <<= 1) {
      int u = __shfl_up(ss, off);
      if (tid >= off) ss += u;
    }
    wpre[tid] = ss - t;
  }
  __syncthreads();
  if (i < n) {
    rs[i] = s - v + wpre[wv];
    degf[i] = (float)(v > 0 ? v : 1);
  }
  if (tid == 1023) bsum[blockIdx.x] = wpre[15] + wsum[15];
}

// scan of block sums folded in: wave 0 of every block redundantly scans bsum
__global__ void k_scan3(int* __restrict__ rs, const int* __restrict__ bsum,
                        int* __restrict__ cursor, int n, int nb) {
  __shared__ int boff_s[64];
  __shared__ int total_s;
  int tid = threadIdx.x;
  if (tid < 64) {
    int v = (tid < nb) ? bsum[tid] : 0;
    int s = v;
#pragma unroll
    for (int off = 1; off < 64; off <<= 1) {
      int t = __shfl_up(s, off);
      if (tid >= off) s += t;
    }
    boff_s[tid] = s - v;
    if (tid == 63) total_s = s;
  }
  __syncthreads();
  int i = blockIdx.x * blockDim.x + tid;
  if (i < n) {
    int r = rs[i] + boff_s[i >> 10];
    rs[i] = r;
    cursor[i] = r;
  }
  if (blockIdx.x == 0 && tid == 0) rs[n] = total_s;
}

__global__ void k_scatter(const int* __restrict__ src, const int* __restrict__ dst,
                          int* __restrict__ cursor, int* __restrict__ csr, int E) {
  int i = blockIdx.x * blockDim.x + threadIdx.x;
  if (i < E) {
    int p = atomicAdd(&cursor[dst[i]], 1);
    csr[p] = src[i];
  }
}

// ---------------- fp32 -> interleaved hi|lo X row ----------------
__global__ void k_split(const float* __restrict__ x, unsigned* __restrict__ X,
                        long n2) {
  long g = (long)blockIdx.x * blockDim.x + threadIdx.x;
  if (g >= n2) return;
  float2 v = ((const float2*)x)[g];
  unsigned short hx = f2bf(v.x), hy = f2bf(v.y);
  unsigned short lx = f2bf(v.x - bf2f(hx)), ly = f2bf(v.y - bf2f(hy));
  long row = g >> 6, p = g & 63;
  X[row * 128 + p] = (unsigned)hx | ((unsigned)hy << 16);
  X[row * 128 + 64 + p] = (unsigned)lx | ((unsigned)ly << 16);
}

// ---------------- all weights pack: frag-order bf16 hi/lo, 10 mats ----------
// frag f = nt*4 + ks; lane l supplies B[k0 + 8*(l>>4) + r][nt*16 + (l&15)]
__global__ void k_packAll(const float* __restrict__ Wl, const float* __restrict__ Wr,
                          const float* __restrict__ pW1, const float* __restrict__ pW2,
                          const float* __restrict__ qW1,
                          unsigned short* __restrict__ hi,
                          unsigned short* __restrict__ lo) {
  int gid = blockIdx.x * blockDim.x + threadIdx.x;
  if (gid >= 10 * 2048) return;
  int mat = gid >> 11;
  const float* Wm;
  if (mat < 3) Wm = Wl + (size_t)mat * 16384;
  else if (mat < 6) Wm = Wr + (size_t)(mat - 3) * 16384;
  else if (mat == 6) Wm = pW1;
  else if (mat == 7) Wm = pW2;
  else Wm = qW1 + (size_t)(mat - 8) * 16384;
  int lane = gid & 63;
  int f = (gid >> 6) & 31;
  int nt = f >> 2, ks = f & 3;
  int nn = nt * 16 + (lane & 15);
  int k0 = ks * 32 + 8 * (lane >> 4);
  size_t dst = (size_t)gid * 8;
#pragma unroll
  for (int r = 0; r < 8; ++r) {
    float w = Wm[(size_t)(k0 + r) * 128 + nn];
    unsigned short h = f2bf(w);
    hi[dst + r] = h;
    lo[dst + r] = f2bf(w - bf2f(h));
  }
}

// biasuv = [qb1 | zeros(128)]
__global__ void k_biasuv(const float* __restrict__ qb1, float* __restrict__ b) {
  int i = threadIdx.x;  // 256
  b[i] = (i < 128) ? qb1[i] : 0.f;
}

// ---------------- mean aggregation over X hi-halves -> dense bf16 B ---------
__global__ void k_aggr(const unsigned short* __restrict__ X,
                       const int* __restrict__ csr, const int* __restrict__ rs,
                       const float* __restrict__ degf,
                       unsigned short* __restrict__ Bd, int n) {
  int gid = blockIdx.x * blockDim.x + threadIdx.x;
  int wid = gid >> 6, lane = gid & 63;
  if (wid >= n) return;
  int s = rs[wid], e = rs[wid + 1];
  const int h = lane >> 4;         // neighbor slot (0..3)
  const int o16 = (lane & 15) * 8; // ushort offset within 256 B hi half
  float a0 = 0.f, a1 = 0.f, a2 = 0.f, a3 = 0.f;
  float a4 = 0.f, a5 = 0.f, a6 = 0.f, a7 = 0.f;
  int j = s;
  for (; j + 7 < e; j += 8) {
    int n0 = csr[j + h];
    int n1 = csr[j + 4 + h];
    uint4 v0 = *(const uint4*)(X + (size_t)n0 * 256 + o16);
    uint4 v1 = *(const uint4*)(X + (size_t)n1 * 256 + o16);
    a0 += lo16f(v0.x) + lo16f(v1.x);
    a1 += hi16f(v0.x) + hi16f(v1.x);
    a2 += lo16f(v0.y) + lo16f(v1.y);
    a3 += hi16f(v0.y) + hi16f(v1.y);
    a4 += lo16f(v0.z) + lo16f(v1.z);
    a5 += hi16f(v0.z) + hi16f(v1.z);
    a6 += lo16f(v0.w) + lo16f(v1.w);
    a7 += hi16f(v0.w) + hi16f(v1.w);
  }
  for (; j < e; j += 4) {
    int idx = j + h;
    bool ok = idx < e;
    int nn = ok ? csr[idx] : 0;
    uint4 v = *(const uint4*)(X + (size_t)nn * 256 + o16);
    float m = ok ? 1.f : 0.f;
    a0 += m * lo16f(v.x); a1 += m * hi16f(v.x);
    a2 += m * lo16f(v.y); a3 += m * hi16f(v.y);
    a4 += m * lo16f(v.z); a5 += m * hi16f(v.z);
    a6 += m * lo16f(v.w); a7 += m * hi16f(v.w);
  }
  a0 += __shfl_xor(a0, 16); a1 += __shfl_xor(a1, 16);
  a2 += __shfl_xor(a2, 16); a3 += __shfl_xor(a3, 16);
  a4 += __shfl_xor(a4, 16); a5 += __shfl_xor(a5, 16);
  a6 += __shfl_xor(a6, 16); a7 += __shfl_xor(a7, 16);
  a0 += __shfl_xor(a0, 32); a1 += __shfl_xor(a1, 32);
  a2 += __shfl_xor(a2, 32); a3 += __shfl_xor(a3, 32);
  a4 += __shfl_xor(a4, 32); a5 += __shfl_xor(a5, 32);
  a6 += __shfl_xor(a6, 32); a7 += __shfl_xor(a7, 32);
  if (lane < 16) {
    float inv = 1.0f / degf[wid];
    unsigned short h0 = f2bf(a0 * inv), h1 = f2bf(a1 * inv);
    unsigned short h2 = f2bf(a2 * inv), h3 = f2bf(a3 * inv);
    unsigned short h4 = f2bf(a4 * inv), h5 = f2bf(a5 * inv);
    unsigned short h6 = f2bf(a6 * inv), h7 = f2bf(a7 * inv);
    uint4 oh;
    oh.x = (unsigned)h0 | ((unsigned)h1 << 16);
    oh.y = (unsigned)h2 | ((unsigned)h3 << 16);
    oh.z = (unsigned)h4 | ((unsigned)h5 << 16);
    oh.w = (unsigned)h6 | ((unsigned)h7 << 16);
    *(uint4*)(Bd + (size_t)wid * 128 + o16) = oh;
  }
}

// ---------------- MFMA GEMM: 8-wave blocks, 16 rows/wave ---------------------
// 512 threads = 8 waves; wave owns 16 rows; 128 rows/block; NT=8, 64 KiB LDS
// -> 2 blocks/CU = 16 waves/CU (4/SIMD, VGPR capped 128). A fragments
// preloaded to registers; weights staged via async global_load_lds.
// mfma(w_frag, x_frag): lane owns col quad -> packed uint2 epilogue stores.
// A0DENSE: phase-0 A is dense bf16 (stride 128, no lo, 2 MFMAs/frag).
// EPI: 0 = relu + interleaved out; 1 = interleaved out; 2 = dense bf16 out.
// uvW/uvO: per-blockIdx.y offsets (weights/bias/output) for fused u|v launch.
template <int NPHASE, int EPI, int A0DENSE>
__global__ __launch_bounds__(512, 4) void k_gemm(
    const unsigned short* __restrict__ A0, const unsigned short* __restrict__ A1,
    const unsigned short* __restrict__ W0h, const unsigned short* __restrict__ W0l,
    const unsigned short* __restrict__ W1h, const unsigned short* __restrict__ W1l,
    const float* __restrict__ bias, unsigned short* __restrict__ O, int nrows,
    long uvW, long uvO) {
  __shared__ unsigned short smem[8 * 4096];  // hi: 16384, lo: 16384 ushorts
  unsigned short* smh = smem;
  unsigned short* sml = smem + 8 * 2048;

  const long yb = blockIdx.y;
  W0h += yb * uvW;
  W0l += yb * uvW;
  bias += yb * 128;
  O += yb * uvO;

  const int tid = threadIdx.x;
  const int lane = tid & 63;
  const int wv = tid >> 6;  // 0..7
  const long row0 = ((long)blockIdx.x * 8 + wv) * 16;
  const bool active = row0 < nrows;
  const int kgrp = (lane >> 4) * 8;

  long r = row0 + (lane & 15);
  const long arow = (r < nrows) ? r : (long)(nrows - 1);

  // issue phase-0 weight staging (async, direct to LDS)
#pragma unroll
  for (int k = 0; k < 4; ++k) {
    int t = tid + k * 512;
    gload_lds16((const uint4*)W0h + t, (uint4*)smh + t);
    gload_lds16((const uint4*)W0l + t, (uint4*)sml + t);
  }

  // preload ALL A fragments into registers (overlaps with weight staging)
  bf16x8 a0h[4], a0l[4], a1h[4], a1l[4];
  if (active) {
#pragma unroll
    for (int ks = 0; ks < 4; ++ks) {
      if (A0DENSE) {
        a0h[ks] = *(const bf16x8*)(A0 + arow * 128 + ks * 32 + kgrp);
      } else {
        a0h[ks] = *(const bf16x8*)(A0 + arow * 256 + ks * 32 + kgrp);
        a0l[ks] = *(const bf16x8*)(A0 + arow * 256 + 128 + ks * 32 + kgrp);
      }
      if (NPHASE == 2) {
        a1h[ks] = *(const bf16x8*)(A1 + arow * 256 + ks * 32 + kgrp);
        a1l[ks] = *(const bf16x8*)(A1 + arow * 256 + 128 + ks * 32 + kgrp);
      }
    }
  }

  f32x4 zero = {0.f, 0.f, 0.f, 0.f};
  f32x4 acc[8];
#pragma unroll
  for (int t = 0; t < 8; ++t) acc[t] = zero;

  __syncthreads();  // phase-0 weights in LDS, A regs ready

  if (active) {
#pragma unroll
    for (int ks = 0; ks < 4; ++ks) {
#pragma unroll
      for (int nt = 0; nt < 8; ++nt) {
        const bf16x8 b_h = *(const bf16x8*)(smh + (nt * 4 + ks) * 512 + lane * 8);
        const bf16x8 b_l = *(const bf16x8*)(sml + (nt * 4 + ks) * 512 + lane * 8);
        acc[nt] = __builtin_amdgcn_mfma_f32_16x16x32_bf16(b_h, a0h[ks], acc[nt], 0, 0, 0);
        if (!A0DENSE)
          acc[nt] = __builtin_amdgcn_mfma_f32_16x16x32_bf16(b_h, a0l[ks], acc[nt], 0, 0, 0);
        acc[nt] = __builtin_amdgcn_mfma_f32_16x16x32_bf16(b_l, a0h[ks], acc[nt], 0, 0, 0);
      }
    }
  }

  if (NPHASE == 2) {
    __syncthreads();  // all waves done reading phase-0 LDS
#pragma unroll
    for (int k = 0; k < 4; ++k) {
      int t = tid + k * 512;
      gload_lds16((const uint4*)W1h + t, (uint4*)smh + t);
      gload_lds16((const uint4*)W1l + t, (uint4*)sml + t);
    }
    __syncthreads();
    if (active) {
#pragma unroll
      for (int ks = 0; ks < 4; ++ks) {
#pragma unroll
        for (int nt = 0; nt < 8; ++nt) {
          const bf16x8 b_h = *(const bf16x8*)(smh + (nt * 4 + ks) * 512 + lane * 8);
          const bf16x8 b_l = *(const bf16x8*)(sml + (nt * 4 + ks) * 512 + lane * 8);
          acc[nt] = __builtin_amdgcn_mfma_f32_16x16x32_bf16(b_h, a1h[ks], acc[nt], 0, 0, 0);
          acc[nt] = __builtin_amdgcn_mfma_f32_16x16x32_bf16(b_h, a1l[ks], acc[nt], 0, 0, 0);
          acc[nt] = __builtin_amdgcn_mfma_f32_16x16x32_bf16(b_l, a1h[ks], acc[nt], 0, 0, 0);
        }
      }
    }
  }
  if (!active) return;

  const int cq = (lane >> 4) * 4;  // col quad base within 16-col tile
  const long row = row0 + (lane & 15);
  if (row >= nrows) return;
#pragma unroll
  for (int nt = 0; nt < 8; ++nt) {
    const int col = nt * 16 + cq;
    float4 bv = *(const float4*)(bias + col);
    float v0 = acc[nt][0] + bv.x;
    float v1 = acc[nt][1] + bv.y;
    float v2 = acc[nt][2] + bv.z;
    float v3 = acc[nt][3] + bv.w;
    if (EPI == 0) {
      v0 = fmaxf(v0, 0.f); v1 = fmaxf(v1, 0.f);
      v2 = fmaxf(v2, 0.f); v3 = fmaxf(v3, 0.f);
    }
    unsigned short h0 = f2bf(v0), h1 = f2bf(v1), h2 = f2bf(v2), h3 = f2bf(v3);
    uint2 oh;
    oh.x = (unsigned)h0 | ((unsigned)h1 << 16);
    oh.y = (unsigned)h2 | ((unsigned)h3 << 16);
    if (EPI == 2) {
      *(uint2*)(O + row * 128 + col) = oh;
    } else {
      uint2 ol;
      ol.x = (unsigned)f2bf(v0 - bf2f(h0)) | ((unsigned)f2bf(v1 - bf2f(h1)) << 16);
      ol.y = (unsigned)f2bf(v2 - bf2f(h2)) | ((unsigned)f2bf(v3 - bf2f(h3)) << 16);
      *(uint2*)(O + row * 256 + col) = oh;
      *(uint2*)(O + row * 256 + 128 + col) = ol;
    }
  }
}

// ---------------- predict pair: y = relu(u[i]+v[j]) . qW2 + qb2 -------------
__global__ __launch_bounds__(256) void k_pair(
    const unsigned short* __restrict__ u, const unsigned short* __restrict__ v,
    const int* __restrict__ ps, const int* __restrict__ pd,
    const float* __restrict__ qW2, const float* __restrict__ qb2,
    float* __restrict__ out, int EP) {
  int gid = blockIdx.x * blockDim.x + threadIdx.x;
  long wid = gid >> 6;
  int lane = gid & 63;
  int sub = lane & 15, g = lane >> 4;
  long base = wid * 8;
  if (base >= EP) return;
  float4 q0 = *(const float4*)(qW2 + sub * 8);
  float4 q1 = *(const float4*)(qW2 + sub * 8 + 4);
  float qb = qb2[0];

  long p0 = base + g;
  long p1 = base + 4 + g;
  long c0 = (p0 < EP) ? p0 : (EP - 1);
  long c1 = (p1 < EP) ? p1 : (EP - 1);
  int i0 = ps[c0], j0 = pd[c0];
  int i1 = ps[c1], j1 = pd[c1];
  uint4 a0 = *(const uint4*)(u + (size_t)i0 * 128 + sub * 8);
  uint4 b0 = *(const uint4*)(v + (size_t)j0 * 128 + sub * 8);
  uint4 a1 = *(const uint4*)(u + (size_t)i1 * 128 + sub * 8);
  uint4 b1 = *(const uint4*)(v + (size_t)j1 * 128 + sub * 8);

  float s0, s1;
  {
    float t;
    t = fmaxf(lo16f(a0.x) + lo16f(b0.x), 0.f) * q0.x;
    t = fmaf(fmaxf(hi16f(a0.x) + hi16f(b0.x), 0.f), q0.y, t);
    t = fmaf(fmaxf(lo16f(a0.y) + lo16f(b0.y), 0.f), q0.z, t);
    t = fmaf(fmaxf(hi16f(a0.y) + hi16f(b0.y), 0.f), q0.w, t);
    t = fmaf(fmaxf(lo16f(a0.z) + lo16f(b0.z), 0.f), q1.x, t);
    t = fmaf(fmaxf(hi16f(a0.z) + hi16f(b0.z), 0.f), q1.y, t);
    t = fmaf(fmaxf(lo16f(a0.w) + lo16f(b0.w), 0.f), q1.z, t);
    t = fmaf(fmaxf(hi16f(a0.w) + hi16f(b0.w), 0.f), q1.w, t);
    s0 = t;
    t = fmaxf(lo16f(a1.x) + lo16f(b1.x), 0.f) * q0.x;
    t = fmaf(fmaxf(hi16f(a1.x) + hi16f(b1.x), 0.f), q0.y, t);
    t = fmaf(fmaxf(lo16f(a1.y) + lo16f(b1.y), 0.f), q0.z, t);
    t = fmaf(fmaxf(hi16f(a1.y) + hi16f(b1.y), 0.f), q0.w, t);
    t = fmaf(fmaxf(lo16f(a1.z) + lo16f(b1.z), 0.f), q1.x, t);
    t = fmaf(fmaxf(hi16f(a1.z) + hi16f(b1.z), 0.f), q1.y, t);
    t = fmaf(fmaxf(lo16f(a1.w) + lo16f(b1.w), 0.f), q1.z, t);
    t = fmaf(fmaxf(hi16f(a1.w) + hi16f(b1.w), 0.f), q1.w, t);
    s1 = t;
  }
#pragma unroll
  for (int m = 1; m < 16; m <<= 1) {
    s0 += __shfl_xor(s0, m);
    s1 += __shfl_xor(s1, m);
  }
  if (sub == 0) {
    if (p0 < EP) out[p0] = s0 + qb;
    if (p1 < EP) out[p1] = s1 + qb;
  }
}

extern "C" void kernel_launch(void* const* d_in, const int* in_sizes, int n_in,
                              void* d_out, int out_size, void* d_ws, size_t ws_size,
                              hipStream_t stream) {
  const float* x_in = (const float*)d_in[0];
  // d_in[1] edge_attr: dead
  const int* ei = (const int*)d_in[2];
  const int* pe = (const int*)d_in[3];
  const float* Wl = (const float*)d_in[4];
  const float* bl = (const float*)d_in[5];
  const float* Wr = (const float*)d_in[6];
  // d_in[7..10] edge-update weights: dead
  const float* pW1 = (const float*)d_in[11];
  const float* pb1 = (const float*)d_in[12];
  const float* pW2 = (const float*)d_in[13];
  const float* pb2 = (const float*)d_in[14];
  const float* qW1 = (const float*)d_in[15];
  const float* qb1 = (const float*)d_in[16];
  const float* qW2 = (const float*)d_in[17];
  const float* qb2 = (const float*)d_in[18];

  const int N = in_sizes[0] / 128;
  const int E = in_sizes[2] / 2;
  const int EP = in_sizes[3] / 2;
  const int* e_src = ei;
  const int* e_dst = ei + E;
  const int* p_src = pe;
  const int* p_dst = pe + EP;

  char* ws = (char*)d_ws;
  size_t off = 0;
  auto alloc = [&](size_t bytes) {
    void* p = ws + off;
    off += (bytes + 511) & ~(size_t)511;
    return p;
  };
  // X: interleaved [node][hi|lo] (512 B rows). B: scratch — dense bf16
  // aggregated mean, then interleaved h1, then u|v.
  unsigned short* X = (unsigned short*)alloc((size_t)N * 256 * 2);  // 25.6 MB
  unsigned short* B = (unsigned short*)alloc((size_t)N * 256 * 2);  // 25.6 MB
  int* deg_i = (int*)alloc((size_t)N * 4);
  int* rs = (int*)alloc((size_t)(N + 1) * 4);
  int* cursor = (int*)alloc((size_t)N * 4);
  float* degf = (float*)alloc((size_t)N * 4);
  int* csr = (int*)alloc((size_t)E * 4);
  int* bsum = (int*)alloc(64 * 4);
  unsigned short* Whi = (unsigned short*)alloc((size_t)10 * 16384 * 2);
  unsigned short* Wlo = (unsigned short*)alloc((size_t)10 * 16384 * 2);
  float* biasuv = (float*)alloc(256 * 4);

  const size_t MS = 16384;  // mat stride in ushorts
  const int nb = (N + 1023) / 1024;

  hipMemsetAsync(deg_i, 0, (size_t)N * 4, stream);
  k_biasuv<<<1, 256, 0, stream>>>(qb1, biasuv);

  // pack all 10 weight mats (frag order, hi/lo split); mats 8,9 = qW1 t/b
  k_packAll<<<(10 * 2048 + 255) / 256, 256, 0, stream>>>(Wl, Wr, pW1, pW2, qW1,
                                                         Whi, Wlo);

  // x -> interleaved hi|lo
  long n2 = (long)N * 64;
  k_split<<<(int)((n2 + 255) / 256), 256, 0, stream>>>(x_in, (unsigned*)X, n2);

  // CSR (hierarchical scan; block-sum scan folded into scan3)
  k_count<<<(E + 255) / 256, 256, 0, stream>>>(e_dst, deg_i, E);
  k_scan1<<<nb, 1024, 0, stream>>>(deg_i, rs, degf, bsum, N);
  k_scan3<<<(N + 255) / 256, 256, 0, stream>>>(rs, bsum, cursor, N, nb);
  k_scatter<<<(E + 255) / 256, 256, 0, stream>>>(e_src, e_dst, cursor, csr, E);

  const int gmm = (N + 127) / 128;  // 128 rows/block, 8 waves
  const int agblocks = (N + 3) / 4;
  for (int l = 0; l < 3; ++l) {
    k_aggr<<<agblocks, 256, 0, stream>>>(X, csr, rs, degf, B, N);
    // x = relu(aggr@Wl + x@Wr + bl) -> X interleaved; aggr (B) is dense bf16
    // (in-place safe: rows wave-owned; A preloads precede epilogue stores)
    k_gemm<2, 0, 1><<<gmm, 512, 0, stream>>>(
        B, X, Whi + (size_t)l * MS, Wlo + (size_t)l * MS,
        Whi + (size_t)(3 + l) * MS, Wlo + (size_t)(3 + l) * MS,
        bl + (size_t)l * 128, X, N, 0, 0);
  }
  // h1 = relu(x@pW1+pb1) -> B (interleaved)
  k_gemm<1, 0, 0><<<gmm, 512, 0, stream>>>(
      X, nullptr, Whi + 6 * MS, Wlo + 6 * MS, nullptr, nullptr, pb1, B, N, 0, 0);
  // x2 = h1@pW2+pb2 -> X (in-place over x; B is the source)
  k_gemm<1, 1, 0><<<gmm, 512, 0, stream>>>(
      B, nullptr, Whi + 7 * MS, Wlo + 7 * MS, nullptr, nullptr, pb2, X, N, 0, 0);
  // u = x2@qW1t + qb1 ; v = x2@qW1b — ONE dispatch, gridDim.y selects mat/out
  unsigned short* u = B;
  unsigned short* v = B + (size_t)N * 128;
  k_gemm<1, 2, 0><<<dim3(gmm, 2), 512, 0, stream>>>(
      X, nullptr, Whi + 8 * MS, Wlo + 8 * MS, nullptr, nullptr, biasuv, u, N,
      (long)MS, (long)N * 128);
  // y = relu(u[i]+v[j]) . qW2 + qb2
  k_pair<<<(EP + 31) / 32, 256, 0, stream>>>(u, v, p_src, p_dst, qW2, qb2,
                                             (float*)d_out, EP);
}

// Round 13
// 287.879 us; speedup vs baseline: 1.1118x; 1.0934x over previous
//
#include <hip/hip_runtime.h>

// ---------------------------------------------------------------------------
// GNNStack — dead-code-eliminated (edge-update MLPs never reach the output).
// Matmuls on MFMA bf16, split precision where it matters:
//   X (node features): interleaved [node][hi 128 | lo 128] bf16 (512 B row)
//   B (aggregated mean): dense bf16 (256 B row) — inputs already bf16.
//   C = Ahi*Bhi (+ Alo*Bhi if A has lo) + Ahi*Blo, fp32 AGPR accum.
// Layer GEMM: swapped MFMA operands, 8-wave blocks, 16 rows/wave.
// Post-pipeline h1->x2->u|v FUSED into one kernel: intermediates never hit
// global memory; acc -> next A-frag via per-wave 16x128 LDS bounce
// (XOR-swizzled); LDS ping-pongs between weight-stage and transpose roles.
// ---------------------------------------------------------------------------

typedef __attribute__((ext_vector_type(8))) short bf16x8;
typedef __attribute__((ext_vector_type(4))) float f32x4;

__device__ __forceinline__ unsigned short f2bf(float x) {
  unsigned u = __float_as_uint(x);
  u += 0x7fffu + ((u >> 16) & 1u);
  return (unsigned short)(u >> 16);
}
__device__ __forceinline__ float bf2f(unsigned short h) {
  return __uint_as_float(((unsigned)h) << 16);
}
__device__ __forceinline__ float lo16f(unsigned u) { return __uint_as_float(u << 16); }
__device__ __forceinline__ float hi16f(unsigned u) { return __uint_as_float(u & 0xffff0000u); }

// async global -> LDS, 16 bytes per lane (wave-uniform base + lane*16 pattern)
__device__ __forceinline__ void gload_lds16(const void* g, void* l) {
  __builtin_amdgcn_global_load_lds(
      (const __attribute__((address_space(1))) unsigned int*)g,
      (__attribute__((address_space(3))) unsigned int*)l, 16, 0, 0);
}

// ---------------- CSR build ----------------
__global__ void k_count(const int* __restrict__ dst, int* __restrict__ cnt, int E) {
  int i = blockIdx.x * blockDim.x + threadIdx.x;
  if (i < E) atomicAdd(&cnt[dst[i]], 1);
}

__global__ void k_scan1(const int* __restrict__ cnt, int* __restrict__ rs,
                        float* __restrict__ degf, int* __restrict__ bsum, int n) {
  __shared__ int wsum[16];
  __shared__ int wpre[16];
  const int tid = threadIdx.x;
  const int lane = tid & 63;
  const int wv = tid >> 6;
  int i = blockIdx.x * 1024 + tid;
  int v = (i < n) ? cnt[i] : 0;
  int s = v;
#pragma unroll
  for (int off = 1; off < 64; off <<= 1) {
    int t = __shfl_up(s, off);
    if (lane >= off) s += t;
  }
  if (lane == 63) wsum[wv] = s;
  __syncthreads();
  if (tid < 16) {
    int t = wsum[tid];
    int ss = t;
#pragma unroll
    for (int off = 1; off < 16; off <<= 1) {
      int u = __shfl_up(ss, off);
      if (tid >= off) ss += u;
    }
    wpre[tid] = ss - t;
  }
  __syncthreads();
  if (i < n) {
    rs[i] = s - v + wpre[wv];
    degf[i] = (float)(v > 0 ? v : 1);
  }
  if (tid == 1023) bsum[blockIdx.x] = wpre[15] + wsum[15];
}

// scan of block sums folded in: wave 0 of every block redundantly scans bsum
__global__ void k_scan3(int* __restrict__ rs, const int* __restrict__ bsum,
                        int* __restrict__ cursor, int n, int nb) {
  __shared__ int boff_s[64];
  __shared__ int total_s;
  int tid = threadIdx.x;
  if (tid < 64) {
    int v = (tid < nb) ? bsum[tid] : 0;
    int s = v;
#pragma unroll
    for (int off = 1; off < 64; off <<= 1) {
      int t = __shfl_up(s, off);
      if (tid >= off) s += t;
    }
    boff_s[tid] = s - v;
    if (tid == 63) total_s = s;
  }
  __syncthreads();
  int i = blockIdx.x * blockDim.x + tid;
  if (i < n) {
    int r = rs[i] + boff_s[i >> 10];
    rs[i] = r;
    cursor[i] = r;
  }
  if (blockIdx.x == 0 && tid == 0) rs[n] = total_s;
}

__global__ void k_scatter(const int* __restrict__ src, const int* __restrict__ dst,
                          int* __restrict__ cursor, int* __restrict__ csr, int E) {
  int i = blockIdx.x * blockDim.x + threadIdx.x;
  if (i < E) {
    int p = atomicAdd(&cursor[dst[i]], 1);
    csr[p] = src[i];
  }
}

// ---------------- fp32 -> interleaved hi|lo X row ----------------
__global__ void k_split(const float* __restrict__ x, unsigned* __restrict__ X,
                        long n2) {
  long g = (long)blockIdx.x * blockDim.x + threadIdx.x;
  if (g >= n2) return;
  float2 v = ((const float2*)x)[g];
  unsigned short hx = f2bf(v.x), hy = f2bf(v.y);
  unsigned short lx = f2bf(v.x - bf2f(hx)), ly = f2bf(v.y - bf2f(hy));
  long row = g >> 6, p = g & 63;
  X[row * 128 + p] = (unsigned)hx | ((unsigned)hy << 16);
  X[row * 128 + 64 + p] = (unsigned)lx | ((unsigned)ly << 16);
}

// ---------------- all weights pack: frag-order bf16 hi/lo, 10 mats ----------
// frag f = nt*4 + ks; lane l supplies B[k0 + 8*(l>>4) + r][nt*16 + (l&15)]
__global__ void k_packAll(const float* __restrict__ Wl, const float* __restrict__ Wr,
                          const float* __restrict__ pW1, const float* __restrict__ pW2,
                          const float* __restrict__ qW1,
                          unsigned short* __restrict__ hi,
                          unsigned short* __restrict__ lo) {
  int gid = blockIdx.x * blockDim.x + threadIdx.x;
  if (gid >= 10 * 2048) return;
  int mat = gid >> 11;
  const float* Wm;
  if (mat < 3) Wm = Wl + (size_t)mat * 16384;
  else if (mat < 6) Wm = Wr + (size_t)(mat - 3) * 16384;
  else if (mat == 6) Wm = pW1;
  else if (mat == 7) Wm = pW2;
  else Wm = qW1 + (size_t)(mat - 8) * 16384;
  int lane = gid & 63;
  int f = (gid >> 6) & 31;
  int nt = f >> 2, ks = f & 3;
  int nn = nt * 16 + (lane & 15);
  int k0 = ks * 32 + 8 * (lane >> 4);
  size_t dst = (size_t)gid * 8;
#pragma unroll
  for (int r = 0; r < 8; ++r) {
    float w = Wm[(size_t)(k0 + r) * 128 + nn];
    unsigned short h = f2bf(w);
    hi[dst + r] = h;
    lo[dst + r] = f2bf(w - bf2f(h));
  }
}

// ---------------- mean aggregation over X hi-halves -> dense bf16 B ---------
__global__ void k_aggr(const unsigned short* __restrict__ X,
                       const int* __restrict__ csr, const int* __restrict__ rs,
                       const float* __restrict__ degf,
                       unsigned short* __restrict__ Bd, int n) {
  int gid = blockIdx.x * blockDim.x + threadIdx.x;
  int wid = gid >> 6, lane = gid & 63;
  if (wid >= n) return;
  int s = rs[wid], e = rs[wid + 1];
  const int h = lane >> 4;         // neighbor slot (0..3)
  const int o16 = (lane & 15) * 8; // ushort offset within 256 B hi half
  float a0 = 0.f, a1 = 0.f, a2 = 0.f, a3 = 0.f;
  float a4 = 0.f, a5 = 0.f, a6 = 0.f, a7 = 0.f;
  int j = s;
  for (; j + 7 < e; j += 8) {
    int n0 = csr[j + h];
    int n1 = csr[j + 4 + h];
    uint4 v0 = *(const uint4*)(X + (size_t)n0 * 256 + o16);
    uint4 v1 = *(const uint4*)(X + (size_t)n1 * 256 + o16);
    a0 += lo16f(v0.x) + lo16f(v1.x);
    a1 += hi16f(v0.x) + hi16f(v1.x);
    a2 += lo16f(v0.y) + lo16f(v1.y);
    a3 += hi16f(v0.y) + hi16f(v1.y);
    a4 += lo16f(v0.z) + lo16f(v1.z);
    a5 += hi16f(v0.z) + hi16f(v1.z);
    a6 += lo16f(v0.w) + lo16f(v1.w);
    a7 += hi16f(v0.w) + hi16f(v1.w);
  }
  for (; j < e; j += 4) {
    int idx = j + h;
    bool ok = idx < e;
    int nn = ok ? csr[idx] : 0;
    uint4 v = *(const uint4*)(X + (size_t)nn * 256 + o16);
    float m = ok ? 1.f : 0.f;
    a0 += m * lo16f(v.x); a1 += m * hi16f(v.x);
    a2 += m * lo16f(v.y); a3 += m * hi16f(v.y);
    a4 += m * lo16f(v.z); a5 += m * hi16f(v.z);
    a6 += m * lo16f(v.w); a7 += m * hi16f(v.w);
  }
  a0 += __shfl_xor(a0, 16); a1 += __shfl_xor(a1, 16);
  a2 += __shfl_xor(a2, 16); a3 += __shfl_xor(a3, 16);
  a4 += __shfl_xor(a4, 16); a5 += __shfl_xor(a5, 16);
  a6 += __shfl_xor(a6, 16); a7 += __shfl_xor(a7, 16);
  a0 += __shfl_xor(a0, 32); a1 += __shfl_xor(a1, 32);
  a2 += __shfl_xor(a2, 32); a3 += __shfl_xor(a3, 32);
  a4 += __shfl_xor(a4, 32); a5 += __shfl_xor(a5, 32);
  a6 += __shfl_xor(a6, 32); a7 += __shfl_xor(a7, 32);
  if (lane < 16) {
    float inv = 1.0f / degf[wid];
    unsigned short h0 = f2bf(a0 * inv), h1 = f2bf(a1 * inv);
    unsigned short h2 = f2bf(a2 * inv), h3 = f2bf(a3 * inv);
    unsigned short h4 = f2bf(a4 * inv), h5 = f2bf(a5 * inv);
    unsigned short h6 = f2bf(a6 * inv), h7 = f2bf(a7 * inv);
    uint4 oh;
    oh.x = (unsigned)h0 | ((unsigned)h1 << 16);
    oh.y = (unsigned)h2 | ((unsigned)h3 << 16);
    oh.z = (unsigned)h4 | ((unsigned)h5 << 16);
    oh.w = (unsigned)h6 | ((unsigned)h7 << 16);
    *(uint4*)(Bd + (size_t)wid * 128 + o16) = oh;
  }
}

// ---------------- MFMA building blocks --------------------------------------
__device__ __forceinline__ void mm3term(f32x4 acc[8], const bf16x8 a_h[4],
                                        const bf16x8 a_l[4],
                                        const unsigned short* smh,
                                        const unsigned short* sml, int lane) {
#pragma unroll
  for (int ks = 0; ks < 4; ++ks)
#pragma unroll
    for (int nt = 0; nt < 8; ++nt) {
      const bf16x8 b_h = *(const bf16x8*)(smh + (nt * 4 + ks) * 512 + lane * 8);
      const bf16x8 b_l = *(const bf16x8*)(sml + (nt * 4 + ks) * 512 + lane * 8);
      acc[nt] = __builtin_amdgcn_mfma_f32_16x16x32_bf16(b_h, a_h[ks], acc[nt], 0, 0, 0);
      acc[nt] = __builtin_amdgcn_mfma_f32_16x16x32_bf16(b_h, a_l[ks], acc[nt], 0, 0, 0);
      acc[nt] = __builtin_amdgcn_mfma_f32_16x16x32_bf16(b_l, a_h[ks], acc[nt], 0, 0, 0);
    }
}

// acc(+bias,opt relu) -> per-wave 16x128 transpose tile (hi/lo planes, XOR swz)
template <bool RELU>
__device__ __forceinline__ void t_store(const f32x4 acc[8], const float* bias,
                                        unsigned short* tw, int r16, int cq) {
#pragma unroll
  for (int nt = 0; nt < 8; ++nt) {
    int col = nt * 16 + cq;
    float4 bv = *(const float4*)(bias + col);
    float v0 = acc[nt][0] + bv.x, v1 = acc[nt][1] + bv.y;
    float v2 = acc[nt][2] + bv.z, v3 = acc[nt][3] + bv.w;
    if (RELU) {
      v0 = fmaxf(v0, 0.f); v1 = fmaxf(v1, 0.f);
      v2 = fmaxf(v2, 0.f); v3 = fmaxf(v3, 0.f);
    }
    unsigned short h0 = f2bf(v0), h1 = f2bf(v1), h2 = f2bf(v2), h3 = f2bf(v3);
    uint2 oh, ol;
    oh.x = (unsigned)h0 | ((unsigned)h1 << 16);
    oh.y = (unsigned)h2 | ((unsigned)h3 << 16);
    ol.x = (unsigned)f2bf(v0 - bf2f(h0)) | ((unsigned)f2bf(v1 - bf2f(h1)) << 16);
    ol.y = (unsigned)f2bf(v2 - bf2f(h2)) | ((unsigned)f2bf(v3 - bf2f(h3)) << 16);
    int idx = (r16 * 128 + col) ^ ((r16 & 7) << 3);
    *(uint2*)(tw + idx) = oh;
    *(uint2*)(tw + 2048 + idx) = ol;
  }
}

__device__ __forceinline__ void t_load(bf16x8 a_h[4], bf16x8 a_l[4],
                                       const unsigned short* tw, int r16, int kgrp) {
#pragma unroll
  for (int ks = 0; ks < 4; ++ks) {
    int idx = (r16 * 128 + ks * 32 + kgrp) ^ ((r16 & 7) << 3);
    a_h[ks] = *(const bf16x8*)(tw + idx);
    a_l[ks] = *(const bf16x8*)(tw + 2048 + idx);
  }
}

// ---------------- layer GEMM: 8-wave blocks, 16 rows/wave --------------------
// x = relu(B@Wl + X@Wr + bl) -> X interleaved. B dense (phase 0, 2 MFMAs).
__global__ __launch_bounds__(512, 4) void k_gemm(
    const unsigned short* __restrict__ A0, const unsigned short* __restrict__ A1,
    const unsigned short* __restrict__ W0h, const unsigned short* __restrict__ W0l,
    const unsigned short* __restrict__ W1h, const unsigned short* __restrict__ W1l,
    const float* __restrict__ bias, unsigned short* __restrict__ O, int nrows) {
  __shared__ unsigned short smem[32768];
  unsigned short* smh = smem;
  unsigned short* sml = smem + 16384;

  const int tid = threadIdx.x;
  const int lane = tid & 63;
  const int wv = tid >> 6;
  const long row0 = ((long)blockIdx.x * 8 + wv) * 16;
  const bool active = row0 < nrows;
  const int kgrp = (lane >> 4) * 8;

  long r = row0 + (lane & 15);
  const long arow = (r < nrows) ? r : (long)(nrows - 1);

#pragma unroll
  for (int k = 0; k < 4; ++k) {
    int t = tid + k * 512;
    gload_lds16((const uint4*)W0h + t, (uint4*)smh + t);
    gload_lds16((const uint4*)W0l + t, (uint4*)sml + t);
  }

  bf16x8 a0h[4], a1h[4], a1l[4];
  if (active) {
#pragma unroll
    for (int ks = 0; ks < 4; ++ks) {
      a0h[ks] = *(const bf16x8*)(A0 + arow * 128 + ks * 32 + kgrp);
      a1h[ks] = *(const bf16x8*)(A1 + arow * 256 + ks * 32 + kgrp);
      a1l[ks] = *(const bf16x8*)(A1 + arow * 256 + 128 + ks * 32 + kgrp);
    }
  }

  f32x4 zero = {0.f, 0.f, 0.f, 0.f};
  f32x4 acc[8];
#pragma unroll
  for (int t = 0; t < 8; ++t) acc[t] = zero;

  __syncthreads();

  if (active) {
#pragma unroll
    for (int ks = 0; ks < 4; ++ks)
#pragma unroll
      for (int nt = 0; nt < 8; ++nt) {
        const bf16x8 b_h = *(const bf16x8*)(smh + (nt * 4 + ks) * 512 + lane * 8);
        const bf16x8 b_l = *(const bf16x8*)(sml + (nt * 4 + ks) * 512 + lane * 8);
        acc[nt] = __builtin_amdgcn_mfma_f32_16x16x32_bf16(b_h, a0h[ks], acc[nt], 0, 0, 0);
        acc[nt] = __builtin_amdgcn_mfma_f32_16x16x32_bf16(b_l, a0h[ks], acc[nt], 0, 0, 0);
      }
  }

  __syncthreads();
#pragma unroll
  for (int k = 0; k < 4; ++k) {
    int t = tid + k * 512;
    gload_lds16((const uint4*)W1h + t, (uint4*)smh + t);
    gload_lds16((const uint4*)W1l + t, (uint4*)sml + t);
  }
  __syncthreads();
  if (!active) return;

  mm3term(acc, a1h, a1l, smh, sml, lane);

  const int cq = (lane >> 4) * 4;
  const long row = row0 + (lane & 15);
  if (row >= nrows) return;
#pragma unroll
  for (int nt = 0; nt < 8; ++nt) {
    const int col = nt * 16 + cq;
    float4 bv = *(const float4*)(bias + col);
    float v0 = fmaxf(acc[nt][0] + bv.x, 0.f);
    float v1 = fmaxf(acc[nt][1] + bv.y, 0.f);
    float v2 = fmaxf(acc[nt][2] + bv.z, 0.f);
    float v3 = fmaxf(acc[nt][3] + bv.w, 0.f);
    unsigned short h0 = f2bf(v0), h1 = f2bf(v1), h2 = f2bf(v2), h3 = f2bf(v3);
    uint2 oh, ol;
    oh.x = (unsigned)h0 | ((unsigned)h1 << 16);
    oh.y = (unsigned)h2 | ((unsigned)h3 << 16);
    ol.x = (unsigned)f2bf(v0 - bf2f(h0)) | ((unsigned)f2bf(v1 - bf2f(h1)) << 16);
    ol.y = (unsigned)f2bf(v2 - bf2f(h2)) | ((unsigned)f2bf(v3 - bf2f(h3)) << 16);
    *(uint2*)(O + row * 256 + col) = oh;
    *(uint2*)(O + row * 256 + 128 + col) = ol;
  }
}

// ---------------- fused post pipeline: h1 -> x2 -> u|v ----------------------
// One kernel, intermediates in registers; acc -> A-frag via per-wave LDS
// bounce; 64 KiB LDS ping-pongs between weight staging and transpose tiles.
__global__ __launch_bounds__(512, 2) void k_post(
    const unsigned short* __restrict__ X,
    const unsigned short* __restrict__ W1h, const unsigned short* __restrict__ W1l,
    const unsigned short* __restrict__ W2h, const unsigned short* __restrict__ W2l,
    const unsigned short* __restrict__ W3h, const unsigned short* __restrict__ W3l,
    const unsigned short* __restrict__ W4h, const unsigned short* __restrict__ W4l,
    const float* __restrict__ b1, const float* __restrict__ b2,
    const float* __restrict__ b3, const float* __restrict__ b4,
    unsigned short* __restrict__ U, unsigned short* __restrict__ V, int nrows) {
  __shared__ unsigned short smem[32768];  // weights OR 8x per-wave 16x128 tiles
  unsigned short* smh = smem;
  unsigned short* sml = smem + 16384;

  const int tid = threadIdx.x;
  const int lane = tid & 63;
  const int wv = tid >> 6;
  const long row0 = ((long)blockIdx.x * 8 + wv) * 16;
  const bool active = row0 < nrows;
  const int kgrp = (lane >> 4) * 8;
  const int r16 = lane & 15;
  const int cq = (lane >> 4) * 4;
  unsigned short* tw = smem + wv * 4096;  // wave tile: hi[2048] | lo[2048]

  long rr = row0 + r16;
  const long arow = (rr < nrows) ? rr : (long)(nrows - 1);
  const long row = row0 + r16;

  // ---- stage pW1; preload X frags ----
#pragma unroll
  for (int k = 0; k < 4; ++k) {
    int t = tid + k * 512;
    gload_lds16((const uint4*)W1h + t, (uint4*)smh + t);
    gload_lds16((const uint4*)W1l + t, (uint4*)sml + t);
  }
  bf16x8 a_h[4], a_l[4];
  if (active) {
#pragma unroll
    for (int ks = 0; ks < 4; ++ks) {
      a_h[ks] = *(const bf16x8*)(X + arow * 256 + ks * 32 + kgrp);
      a_l[ks] = *(const bf16x8*)(X + arow * 256 + 128 + ks * 32 + kgrp);
    }
  }
  f32x4 zero = {0.f, 0.f, 0.f, 0.f};
  f32x4 acc[8];
#pragma unroll
  for (int t = 0; t < 8; ++t) acc[t] = zero;

  __syncthreads();  // pW1 staged
  if (active) mm3term(acc, a_h, a_l, smh, sml, lane);  // h1 pre-act
  __syncthreads();  // all waves done reading pW1 -> region free for tiles

  if (active) {
    t_store<true>(acc, b1, tw, r16, cq);   // h1 = relu(.+b1) -> tile
    t_load(a_h, a_l, tw, r16, kgrp);       // h1 frags (wave-local)
  }
  __syncthreads();  // all waves done with tiles -> stage pW2

#pragma unroll
  for (int k = 0; k < 4; ++k) {
    int t = tid + k * 512;
    gload_lds16((const uint4*)W2h + t, (uint4*)smh + t);
    gload_lds16((const uint4*)W2l + t, (uint4*)sml + t);
  }
#pragma unroll
  for (int t = 0; t < 8; ++t) acc[t] = zero;
  __syncthreads();  // pW2 staged
  if (active) mm3term(acc, a_h, a_l, smh, sml, lane);  // x2 pre-act
  __syncthreads();  // pW2 region free

  if (active) {
    t_store<false>(acc, b2, tw, r16, cq);  // x2 = . + b2 -> tile
    t_load(a_h, a_l, tw, r16, kgrp);       // x2 frags (persist for u AND v)
  }
  __syncthreads();  // tiles free -> stage qW1t

#pragma unroll
  for (int k = 0; k < 4; ++k) {
    int t = tid + k * 512;
    gload_lds16((const uint4*)W3h + t, (uint4*)smh + t);
    gload_lds16((const uint4*)W3l + t, (uint4*)sml + t);
  }
#pragma unroll
  for (int t = 0; t < 8; ++t) acc[t] = zero;
  __syncthreads();  // qW1t staged
  if (active) mm3term(acc, a_h, a_l, smh, sml, lane);  // u pre-bias
  if (active && row < nrows) {
#pragma unroll
    for (int nt = 0; nt < 8; ++nt) {
      const int col = nt * 16 + cq;
      float4 bv = *(const float4*)(b3 + col);
      unsigned short h0 = f2bf(acc[nt][0] + bv.x), h1 = f2bf(acc[nt][1] + bv.y);
      unsigned short h2 = f2bf(acc[nt][2] + bv.z), h3 = f2bf(acc[nt][3] + bv.w);
      uint2 oh;
      oh.x = (unsigned)h0 | ((unsigned)h1 << 16);
      oh.y = (unsigned)h2 | ((unsigned)h3 << 16);
      *(uint2*)(U + row * 128 + col) = oh;
    }
  }
  __syncthreads();  // qW1t region free -> stage qW1b

#pragma unroll
  for (int k = 0; k < 4; ++k) {
    int t = tid + k * 512;
    gload_lds16((const uint4*)W4h + t, (uint4*)smh + t);
    gload_lds16((const uint4*)W4l + t, (uint4*)sml + t);
  }
#pragma unroll
  for (int t = 0; t < 8; ++t) acc[t] = zero;
  __syncthreads();  // qW1b staged
  if (!active || row >= nrows) return;
  mm3term(acc, a_h, a_l, smh, sml, lane);  // v pre-bias
#pragma unroll
  for (int nt = 0; nt < 8; ++nt) {
    const int col = nt * 16 + cq;
    float4 bv = *(const float4*)(b4 + col);
    unsigned short h0 = f2bf(acc[nt][0] + bv.x), h1 = f2bf(acc[nt][1] + bv.y);
    unsigned short h2 = f2bf(acc[nt][2] + bv.z), h3 = f2bf(acc[nt][3] + bv.w);
    uint2 oh;
    oh.x = (unsigned)h0 | ((unsigned)h1 << 16);
    oh.y = (unsigned)h2 | ((unsigned)h3 << 16);
    *(uint2*)(V + row * 128 + col) = oh;
  }
}

// ---------------- predict pair: y = relu(u[i]+v[j]) . qW2 + qb2 -------------
__global__ __launch_bounds__(256) void k_pair(
    const unsigned short* __restrict__ u, const unsigned short* __restrict__ v,
    const int* __restrict__ ps, const int* __restrict__ pd,
    const float* __restrict__ qW2, const float* __restrict__ qb2,
    float* __restrict__ out, int EP) {
  int gid = blockIdx.x * blockDim.x + threadIdx.x;
  long wid = gid >> 6;
  int lane = gid & 63;
  int sub = lane & 15, g = lane >> 4;
  long base = wid * 8;
  if (base >= EP) return;
  float4 q0 = *(const float4*)(qW2 + sub * 8);
  float4 q1 = *(const float4*)(qW2 + sub * 8 + 4);
  float qb = qb2[0];

  long p0 = base + g;
  long p1 = base + 4 + g;
  long c0 = (p0 < EP) ? p0 : (EP - 1);
  long c1 = (p1 < EP) ? p1 : (EP - 1);
  int i0 = ps[c0], j0 = pd[c0];
  int i1 = ps[c1], j1 = pd[c1];
  uint4 a0 = *(const uint4*)(u + (size_t)i0 * 128 + sub * 8);
  uint4 b0 = *(const uint4*)(v + (size_t)j0 * 128 + sub * 8);
  uint4 a1 = *(const uint4*)(u + (size_t)i1 * 128 + sub * 8);
  uint4 b1 = *(const uint4*)(v + (size_t)j1 * 128 + sub * 8);

  float s0, s1;
  {
    float t;
    t = fmaxf(lo16f(a0.x) + lo16f(b0.x), 0.f) * q0.x;
    t = fmaf(fmaxf(hi16f(a0.x) + hi16f(b0.x), 0.f), q0.y, t);
    t = fmaf(fmaxf(lo16f(a0.y) + lo16f(b0.y), 0.f), q0.z, t);
    t = fmaf(fmaxf(hi16f(a0.y) + hi16f(b0.y), 0.f), q0.w, t);
    t = fmaf(fmaxf(lo16f(a0.z) + lo16f(b0.z), 0.f), q1.x, t);
    t = fmaf(fmaxf(hi16f(a0.z) + hi16f(b0.z), 0.f), q1.y, t);
    t = fmaf(fmaxf(lo16f(a0.w) + lo16f(b0.w), 0.f), q1.z, t);
    t = fmaf(fmaxf(hi16f(a0.w) + hi16f(b0.w), 0.f), q1.w, t);
    s0 = t;
    t = fmaxf(lo16f(a1.x) + lo16f(b1.x), 0.f) * q0.x;
    t = fmaf(fmaxf(hi16f(a1.x) + hi16f(b1.x), 0.f), q0.y, t);
    t = fmaf(fmaxf(lo16f(a1.y) + lo16f(b1.y), 0.f), q0.z, t);
    t = fmaf(fmaxf(hi16f(a1.y) + hi16f(b1.y), 0.f), q0.w, t);
    t = fmaf(fmaxf(lo16f(a1.z) + lo16f(b1.z), 0.f), q1.x, t);
    t = fmaf(fmaxf(hi16f(a1.z) + hi16f(b1.z), 0.f), q1.y, t);
    t = fmaf(fmaxf(lo16f(a1.w) + lo16f(b1.w), 0.f), q1.z, t);
    t = fmaf(fmaxf(hi16f(a1.w) + hi16f(b1.w), 0.f), q1.w, t);
    s1 = t;
  }
#pragma unroll
  for (int m = 1; m < 16; m <<= 1) {
    s0 += __shfl_xor(s0, m);
    s1 += __shfl_xor(s1, m);
  }
  if (sub == 0) {
    if (p0 < EP) out[p0] = s0 + qb;
    if (p1 < EP) out[p1] = s1 + qb;
  }
}

extern "C" void kernel_launch(void* const* d_in, const int* in_sizes, int n_in,
                              void* d_out, int out_size, void* d_ws, size_t ws_size,
                              hipStream_t stream) {
  const float* x_in = (const float*)d_in[0];
  // d_in[1] edge_attr: dead
  const int* ei = (const int*)d_in[2];
  const int* pe = (const int*)d_in[3];
  const float* Wl = (const float*)d_in[4];
  const float* bl = (const float*)d_in[5];
  const float* Wr = (const float*)d_in[6];
  // d_in[7..10] edge-update weights: dead
  const float* pW1 = (const float*)d_in[11];
  const float* pb1 = (const float*)d_in[12];
  const float* pW2 = (const float*)d_in[13];
  const float* pb2 = (const float*)d_in[14];
  const float* qW1 = (const float*)d_in[15];
  const float* qb1 = (const float*)d_in[16];
  const float* qW2 = (const float*)d_in[17];
  const float* qb2 = (const float*)d_in[18];

  const int N = in_sizes[0] / 128;
  const int E = in_sizes[2] / 2;
  const int EP = in_sizes[3] / 2;
  const int* e_src = ei;
  const int* e_dst = ei + E;
  const int* p_src = pe;
  const int* p_dst = pe + EP;

  char* ws = (char*)d_ws;
  size_t off = 0;
  auto alloc = [&](size_t bytes) {
    void* p = ws + off;
    off += (bytes + 511) & ~(size_t)511;
    return p;
  };
  // X: interleaved [node][hi|lo] (512 B rows). B: dense bf16 aggregated mean,
  // then u|v.
  unsigned short* X = (unsigned short*)alloc((size_t)N * 256 * 2);  // 25.6 MB
  unsigned short* B = (unsigned short*)alloc((size_t)N * 256 * 2);  // 25.6 MB
  int* deg_i = (int*)alloc((size_t)N * 4);
  int* rs = (int*)alloc((size_t)(N + 1) * 4);
  int* cursor = (int*)alloc((size_t)N * 4);
  float* degf = (float*)alloc((size_t)N * 4);
  int* csr = (int*)alloc((size_t)E * 4);
  int* bsum = (int*)alloc(64 * 4);
  unsigned short* Whi = (unsigned short*)alloc((size_t)10 * 16384 * 2);
  unsigned short* Wlo = (unsigned short*)alloc((size_t)10 * 16384 * 2);
  float* zerob = (float*)alloc(128 * 4);

  const size_t MS = 16384;  // mat stride in ushorts
  const int nb = (N + 1023) / 1024;

  hipMemsetAsync(deg_i, 0, (size_t)N * 4, stream);
  hipMemsetAsync(zerob, 0, 128 * 4, stream);

  // pack all 10 weight mats (frag order, hi/lo split); mats 8,9 = qW1 t/b
  k_packAll<<<(10 * 2048 + 255) / 256, 256, 0, stream>>>(Wl, Wr, pW1, pW2, qW1,
                                                         Whi, Wlo);

  // x -> interleaved hi|lo
  long n2 = (long)N * 64;
  k_split<<<(int)((n2 + 255) / 256), 256, 0, stream>>>(x_in, (unsigned*)X, n2);

  // CSR (hierarchical scan; block-sum scan folded into scan3)
  k_count<<<(E + 255) / 256, 256, 0, stream>>>(e_dst, deg_i, E);
  k_scan1<<<nb, 1024, 0, stream>>>(deg_i, rs, degf, bsum, N);
  k_scan3<<<(N + 255) / 256, 256, 0, stream>>>(rs, bsum, cursor, N, nb);
  k_scatter<<<(E + 255) / 256, 256, 0, stream>>>(e_src, e_dst, cursor, csr, E);

  const int gmm = (N + 127) / 128;  // 128 rows/block, 8 waves
  const int agblocks = (N + 3) / 4;
  for (int l = 0; l < 3; ++l) {
    k_aggr<<<agblocks, 256, 0, stream>>>(X, csr, rs, degf, B, N);
    // x = relu(aggr@Wl + x@Wr + bl) -> X interleaved; aggr (B) is dense bf16
    // (in-place safe: rows wave-owned; A preloads precede epilogue stores)
    k_gemm<<<gmm, 512, 0, stream>>>(
        B, X, Whi + (size_t)l * MS, Wlo + (size_t)l * MS,
        Whi + (size_t)(3 + l) * MS, Wlo + (size_t)(3 + l) * MS,
        bl + (size_t)l * 128, X, N);
  }
  // fused post pipeline: u = relu-chain(X) @ qW1t + qb1 ; v = ... @ qW1b
  unsigned short* u = B;
  unsigned short* v = B + (size_t)N * 128;
  k_post<<<gmm, 512, 0, stream>>>(
      X, Whi + 6 * MS, Wlo + 6 * MS, Whi + 7 * MS, Wlo + 7 * MS,
      Whi + 8 * MS, Wlo + 8 * MS, Whi + 9 * MS, Wlo + 9 * MS,
      pb1, pb2, qb1, zerob, u, v, N);
  // y = relu(u[i]+v[j]) . qW2 + qb2
  k_pair<<<(EP + 31) / 32, 256, 0, stream>>>(u, v, p_src, p_dst, qW2, qb2,
                                             (float*)d_out, EP);
}

// Round 14
// 283.276 us; speedup vs baseline: 1.1299x; 1.0162x over previous
//
#include <hip/hip_runtime.h>

// ---------------------------------------------------------------------------
// GNNStack — dead-code-eliminated (edge-update MLPs never reach the output).
// Matmuls on MFMA bf16, split precision where it matters:
//   X (node features): interleaved [node][hi 128 | lo 128] bf16 (512 B row)
//   aggregated mean: bf16 hi only (inputs already bf16) — per round-10 A/B.
//   C = Ahi*Bhi (+ Alo*Bhi where A has lo) + Ahi*Blo, fp32 AGPR accum.
// k_layer FUSES mean-aggregation + 2-phase GEMM: each lane gathers its own
// row's neighbors over its own 32-dim slice (4 kgrp-lanes cover one 64B line
// per neighbor -> full coalescing), mean lands directly in the MFMA A-frag.
// X ping-pongs across layers (gather reads all rows; no in-place write).
// Post-pipeline h1->x2->u|v fused (k_post) with per-wave LDS transpose bounce.
// ---------------------------------------------------------------------------

typedef __attribute__((ext_vector_type(8))) short bf16x8;
typedef __attribute__((ext_vector_type(4))) float f32x4;

__device__ __forceinline__ unsigned short f2bf(float x) {
  unsigned u = __float_as_uint(x);
  u += 0x7fffu + ((u >> 16) & 1u);
  return (unsigned short)(u >> 16);
}
__device__ __forceinline__ float bf2f(unsigned short h) {
  return __uint_as_float(((unsigned)h) << 16);
}
__device__ __forceinline__ float lo16f(unsigned u) { return __uint_as_float(u << 16); }
__device__ __forceinline__ float hi16f(unsigned u) { return __uint_as_float(u & 0xffff0000u); }

// async global -> LDS, 16 bytes per lane (wave-uniform base + lane*16 pattern)
__device__ __forceinline__ void gload_lds16(const void* g, void* l) {
  __builtin_amdgcn_global_load_lds(
      (const __attribute__((address_space(1))) unsigned int*)g,
      (__attribute__((address_space(3))) unsigned int*)l, 16, 0, 0);
}

// ---------------- CSR build ----------------
__global__ void k_count(const int* __restrict__ dst, int* __restrict__ cnt, int E) {
  int i = blockIdx.x * blockDim.x + threadIdx.x;
  if (i < E) atomicAdd(&cnt[dst[i]], 1);
}

__global__ void k_scan1(const int* __restrict__ cnt, int* __restrict__ rs,
                        float* __restrict__ degf, int* __restrict__ bsum, int n) {
  __shared__ int wsum[16];
  __shared__ int wpre[16];
  const int tid = threadIdx.x;
  const int lane = tid & 63;
  const int wv = tid >> 6;
  int i = blockIdx.x * 1024 + tid;
  int v = (i < n) ? cnt[i] : 0;
  int s = v;
#pragma unroll
  for (int off = 1; off < 64; off <<= 1) {
    int t = __shfl_up(s, off);
    if (lane >= off) s += t;
  }
  if (lane == 63) wsum[wv] = s;
  __syncthreads();
  if (tid < 16) {
    int t = wsum[tid];
    int ss = t;
#pragma unroll
    for (int off = 1; off < 16; off <<= 1) {
      int u = __shfl_up(ss, off);
      if (tid >= off) ss += u;
    }
    wpre[tid] = ss - t;
  }
  __syncthreads();
  if (i < n) {
    rs[i] = s - v + wpre[wv];
    degf[i] = (float)(v > 0 ? v : 1);
  }
  if (tid == 1023) bsum[blockIdx.x] = wpre[15] + wsum[15];
}

// scan of block sums folded in: wave 0 of every block redundantly scans bsum
__global__ void k_scan3(int* __restrict__ rs, const int* __restrict__ bsum,
                        int* __restrict__ cursor, int n, int nb) {
  __shared__ int boff_s[64];
  __shared__ int total_s;
  int tid = threadIdx.x;
  if (tid < 64) {
    int v = (tid < nb) ? bsum[tid] : 0;
    int s = v;
#pragma unroll
    for (int off = 1; off < 64; off <<= 1) {
      int t = __shfl_up(s, off);
      if (tid >= off) s += t;
    }
    boff_s[tid] = s - v;
    if (tid == 63) total_s = s;
  }
  __syncthreads();
  int i = blockIdx.x * blockDim.x + tid;
  if (i < n) {
    int r = rs[i] + boff_s[i >> 10];
    rs[i] = r;
    cursor[i] = r;
  }
  if (blockIdx.x == 0 && tid == 0) rs[n] = total_s;
}

__global__ void k_scatter(const int* __restrict__ src, const int* __restrict__ dst,
                          int* __restrict__ cursor, int* __restrict__ csr, int E) {
  int i = blockIdx.x * blockDim.x + threadIdx.x;
  if (i < E) {
    int p = atomicAdd(&cursor[dst[i]], 1);
    csr[p] = src[i];
  }
}

// ---------------- fp32 -> interleaved hi|lo X row ----------------
__global__ void k_split(const float* __restrict__ x, unsigned* __restrict__ X,
                        long n2) {
  long g = (long)blockIdx.x * blockDim.x + threadIdx.x;
  if (g >= n2) return;
  float2 v = ((const float2*)x)[g];
  unsigned short hx = f2bf(v.x), hy = f2bf(v.y);
  unsigned short lx = f2bf(v.x - bf2f(hx)), ly = f2bf(v.y - bf2f(hy));
  long row = g >> 6, p = g & 63;
  X[row * 128 + p] = (unsigned)hx | ((unsigned)hy << 16);
  X[row * 128 + 64 + p] = (unsigned)lx | ((unsigned)ly << 16);
}

// ---------------- all weights pack: frag-order bf16 hi/lo, 10 mats ----------
// frag f = nt*4 + ks; lane l supplies B[k0 + 8*(l>>4) + r][nt*16 + (l&15)]
__global__ void k_packAll(const float* __restrict__ Wl, const float* __restrict__ Wr,
                          const float* __restrict__ pW1, const float* __restrict__ pW2,
                          const float* __restrict__ qW1,
                          unsigned short* __restrict__ hi,
                          unsigned short* __restrict__ lo) {
  int gid = blockIdx.x * blockDim.x + threadIdx.x;
  if (gid >= 10 * 2048) return;
  int mat = gid >> 11;
  const float* Wm;
  if (mat < 3) Wm = Wl + (size_t)mat * 16384;
  else if (mat < 6) Wm = Wr + (size_t)(mat - 3) * 16384;
  else if (mat == 6) Wm = pW1;
  else if (mat == 7) Wm = pW2;
  else Wm = qW1 + (size_t)(mat - 8) * 16384;
  int lane = gid & 63;
  int f = (gid >> 6) & 31;
  int nt = f >> 2, ks = f & 3;
  int nn = nt * 16 + (lane & 15);
  int k0 = ks * 32 + 8 * (lane >> 4);
  size_t dst = (size_t)gid * 8;
#pragma unroll
  for (int r = 0; r < 8; ++r) {
    float w = Wm[(size_t)(k0 + r) * 128 + nn];
    unsigned short h = f2bf(w);
    hi[dst + r] = h;
    lo[dst + r] = f2bf(w - bf2f(h));
  }
}

// ---------------- MFMA building blocks --------------------------------------
__device__ __forceinline__ void mm3term(f32x4 acc[8], const bf16x8 a_h[4],
                                        const bf16x8 a_l[4],
                                        const unsigned short* smh,
                                        const unsigned short* sml, int lane) {
#pragma unroll
  for (int ks = 0; ks < 4; ++ks)
#pragma unroll
    for (int nt = 0; nt < 8; ++nt) {
      const bf16x8 b_h = *(const bf16x8*)(smh + (nt * 4 + ks) * 512 + lane * 8);
      const bf16x8 b_l = *(const bf16x8*)(sml + (nt * 4 + ks) * 512 + lane * 8);
      acc[nt] = __builtin_amdgcn_mfma_f32_16x16x32_bf16(b_h, a_h[ks], acc[nt], 0, 0, 0);
      acc[nt] = __builtin_amdgcn_mfma_f32_16x16x32_bf16(b_h, a_l[ks], acc[nt], 0, 0, 0);
      acc[nt] = __builtin_amdgcn_mfma_f32_16x16x32_bf16(b_l, a_h[ks], acc[nt], 0, 0, 0);
    }
}

// acc(+bias,opt relu) -> per-wave 16x128 transpose tile (hi/lo planes, XOR swz)
template <bool RELU>
__device__ __forceinline__ void t_store(const f32x4 acc[8], const float* bias,
                                        unsigned short* tw, int r16, int cq) {
#pragma unroll
  for (int nt = 0; nt < 8; ++nt) {
    int col = nt * 16 + cq;
    float4 bv = *(const float4*)(bias + col);
    float v0 = acc[nt][0] + bv.x, v1 = acc[nt][1] + bv.y;
    float v2 = acc[nt][2] + bv.z, v3 = acc[nt][3] + bv.w;
    if (RELU) {
      v0 = fmaxf(v0, 0.f); v1 = fmaxf(v1, 0.f);
      v2 = fmaxf(v2, 0.f); v3 = fmaxf(v3, 0.f);
    }
    unsigned short h0 = f2bf(v0), h1 = f2bf(v1), h2 = f2bf(v2), h3 = f2bf(v3);
    uint2 oh, ol;
    oh.x = (unsigned)h0 | ((unsigned)h1 << 16);
    oh.y = (unsigned)h2 | ((unsigned)h3 << 16);
    ol.x = (unsigned)f2bf(v0 - bf2f(h0)) | ((unsigned)f2bf(v1 - bf2f(h1)) << 16);
    ol.y = (unsigned)f2bf(v2 - bf2f(h2)) | ((unsigned)f2bf(v3 - bf2f(h3)) << 16);
    int idx = (r16 * 128 + col) ^ ((r16 & 7) << 3);
    *(uint2*)(tw + idx) = oh;
    *(uint2*)(tw + 2048 + idx) = ol;
  }
}

__device__ __forceinline__ void t_load(bf16x8 a_h[4], bf16x8 a_l[4],
                                       const unsigned short* tw, int r16, int kgrp) {
#pragma unroll
  for (int ks = 0; ks < 4; ++ks) {
    int idx = (r16 * 128 + ks * 32 + kgrp) ^ ((r16 & 7) << 3);
    a_h[ks] = *(const bf16x8*)(tw + idx);
    a_l[ks] = *(const bf16x8*)(tw + 2048 + idx);
  }
}

// ---------------- fused layer: per-lane aggregation + 2-phase GEMM ----------
// x_out = relu(mean(Xin[nbrs]) @ Wl + Xin @ Wr + bl). Lane (r16,kgrp) gathers
// dims [ks*32+kgrp,+8) of row row0+r16's neighbors; 4 kgrp-lanes at the same
// neighbor cover one 64B line -> fully coalesced. Mean -> A-frag in regs.
__global__ __launch_bounds__(512, 4) void k_layer(
    const unsigned short* __restrict__ Xin,
    const int* __restrict__ csr, const int* __restrict__ rs,
    const float* __restrict__ degf,
    const unsigned short* __restrict__ W0h, const unsigned short* __restrict__ W0l,
    const unsigned short* __restrict__ W1h, const unsigned short* __restrict__ W1l,
    const float* __restrict__ bias, unsigned short* __restrict__ Xout, int nrows) {
  __shared__ unsigned short smem[32768];
  unsigned short* smh = smem;
  unsigned short* sml = smem + 16384;

  const int tid = threadIdx.x;
  const int lane = tid & 63;
  const int wv = tid >> 6;
  const long row0 = ((long)blockIdx.x * 8 + wv) * 16;
  const bool active = row0 < nrows;
  const int r16 = lane & 15;
  const int kgrp = (lane >> 4) * 8;
  long rr = row0 + r16;
  const long arow = (rr < nrows) ? rr : (long)(nrows - 1);

  // stage phase-0 weights (Wl) async
#pragma unroll
  for (int k = 0; k < 4; ++k) {
    int t = tid + k * 512;
    gload_lds16((const uint4*)W0h + t, (uint4*)smh + t);
    gload_lds16((const uint4*)W0l + t, (uint4*)sml + t);
  }

  // per-lane mean aggregation over own row's neighbors, own 32-dim slice
  float am[4][8];
#pragma unroll
  for (int ks = 0; ks < 4; ++ks)
#pragma unroll
    for (int d = 0; d < 8; ++d) am[ks][d] = 0.f;

  bf16x8 a0h[4];
  if (active) {
    int s = rs[arow], e = rs[arow + 1];
    int j = s;
    for (; j + 1 < e; j += 2) {
      int n0 = csr[j], n1 = csr[j + 1];
      const unsigned short* b0 = Xin + (size_t)n0 * 256 + kgrp;
      const unsigned short* b1 = Xin + (size_t)n1 * 256 + kgrp;
#pragma unroll
      for (int ks = 0; ks < 4; ++ks) {
        uint4 v0 = *(const uint4*)(b0 + ks * 32);
        uint4 v1 = *(const uint4*)(b1 + ks * 32);
        am[ks][0] += lo16f(v0.x) + lo16f(v1.x);
        am[ks][1] += hi16f(v0.x) + hi16f(v1.x);
        am[ks][2] += lo16f(v0.y) + lo16f(v1.y);
        am[ks][3] += hi16f(v0.y) + hi16f(v1.y);
        am[ks][4] += lo16f(v0.z) + lo16f(v1.z);
        am[ks][5] += hi16f(v0.z) + hi16f(v1.z);
        am[ks][6] += lo16f(v0.w) + lo16f(v1.w);
        am[ks][7] += hi16f(v0.w) + hi16f(v1.w);
      }
    }
    if (j < e) {
      int n0 = csr[j];
      const unsigned short* b0 = Xin + (size_t)n0 * 256 + kgrp;
#pragma unroll
      for (int ks = 0; ks < 4; ++ks) {
        uint4 v0 = *(const uint4*)(b0 + ks * 32);
        am[ks][0] += lo16f(v0.x); am[ks][1] += hi16f(v0.x);
        am[ks][2] += lo16f(v0.y); am[ks][3] += hi16f(v0.y);
        am[ks][4] += lo16f(v0.z); am[ks][5] += hi16f(v0.z);
        am[ks][6] += lo16f(v0.w); am[ks][7] += hi16f(v0.w);
      }
    }
    float inv = 1.0f / degf[arow];
#pragma unroll
    for (int ks = 0; ks < 4; ++ks) {
      uint4 p;
      p.x = (unsigned)f2bf(am[ks][0] * inv) | ((unsigned)f2bf(am[ks][1] * inv) << 16);
      p.y = (unsigned)f2bf(am[ks][2] * inv) | ((unsigned)f2bf(am[ks][3] * inv) << 16);
      p.z = (unsigned)f2bf(am[ks][4] * inv) | ((unsigned)f2bf(am[ks][5] * inv) << 16);
      p.w = (unsigned)f2bf(am[ks][6] * inv) | ((unsigned)f2bf(am[ks][7] * inv) << 16);
      union { uint4 u; bf16x8 b; } cvt;
      cvt.u = p;
      a0h[ks] = cvt.b;
    }
  }

  // phase-1 A frags from Xin (hi + lo)
  bf16x8 a1h[4], a1l[4];
  if (active) {
#pragma unroll
    for (int ks = 0; ks < 4; ++ks) {
      a1h[ks] = *(const bf16x8*)(Xin + arow * 256 + ks * 32 + kgrp);
      a1l[ks] = *(const bf16x8*)(Xin + arow * 256 + 128 + ks * 32 + kgrp);
    }
  }

  f32x4 zero = {0.f, 0.f, 0.f, 0.f};
  f32x4 acc[8];
#pragma unroll
  for (int t = 0; t < 8; ++t) acc[t] = zero;

  __syncthreads();  // Wl staged

  if (active) {
#pragma unroll
    for (int ks = 0; ks < 4; ++ks)
#pragma unroll
      for (int nt = 0; nt < 8; ++nt) {
        const bf16x8 b_h = *(const bf16x8*)(smh + (nt * 4 + ks) * 512 + lane * 8);
        const bf16x8 b_l = *(const bf16x8*)(sml + (nt * 4 + ks) * 512 + lane * 8);
        acc[nt] = __builtin_amdgcn_mfma_f32_16x16x32_bf16(b_h, a0h[ks], acc[nt], 0, 0, 0);
        acc[nt] = __builtin_amdgcn_mfma_f32_16x16x32_bf16(b_l, a0h[ks], acc[nt], 0, 0, 0);
      }
  }

  __syncthreads();  // Wl region free
#pragma unroll
  for (int k = 0; k < 4; ++k) {
    int t = tid + k * 512;
    gload_lds16((const uint4*)W1h + t, (uint4*)smh + t);
    gload_lds16((const uint4*)W1l + t, (uint4*)sml + t);
  }
  __syncthreads();  // Wr staged
  if (!active) return;

  mm3term(acc, a1h, a1l, smh, sml, lane);

  const int cq = (lane >> 4) * 4;
  const long row = row0 + r16;
  if (row >= nrows) return;
#pragma unroll
  for (int nt = 0; nt < 8; ++nt) {
    const int col = nt * 16 + cq;
    float4 bv = *(const float4*)(bias + col);
    float v0 = fmaxf(acc[nt][0] + bv.x, 0.f);
    float v1 = fmaxf(acc[nt][1] + bv.y, 0.f);
    float v2 = fmaxf(acc[nt][2] + bv.z, 0.f);
    float v3 = fmaxf(acc[nt][3] + bv.w, 0.f);
    unsigned short h0 = f2bf(v0), h1 = f2bf(v1), h2 = f2bf(v2), h3 = f2bf(v3);
    uint2 oh, ol;
    oh.x = (unsigned)h0 | ((unsigned)h1 << 16);
    oh.y = (unsigned)h2 | ((unsigned)h3 << 16);
    ol.x = (unsigned)f2bf(v0 - bf2f(h0)) | ((unsigned)f2bf(v1 - bf2f(h1)) << 16);
    ol.y = (unsigned)f2bf(v2 - bf2f(h2)) | ((unsigned)f2bf(v3 - bf2f(h3)) << 16);
    *(uint2*)(Xout + row * 256 + col) = oh;
    *(uint2*)(Xout + row * 256 + 128 + col) = ol;
  }
}

// ---------------- fused post pipeline: h1 -> x2 -> u|v ----------------------
__global__ __launch_bounds__(512, 2) void k_post(
    const unsigned short* __restrict__ X,
    const unsigned short* __restrict__ W1h, const unsigned short* __restrict__ W1l,
    const unsigned short* __restrict__ W2h, const unsigned short* __restrict__ W2l,
    const unsigned short* __restrict__ W3h, const unsigned short* __restrict__ W3l,
    const unsigned short* __restrict__ W4h, const unsigned short* __restrict__ W4l,
    const float* __restrict__ b1, const float* __restrict__ b2,
    const float* __restrict__ b3, const float* __restrict__ b4,
    unsigned short* __restrict__ U, unsigned short* __restrict__ V, int nrows) {
  __shared__ unsigned short smem[32768];  // weights OR 8x per-wave 16x128 tiles
  unsigned short* smh = smem;
  unsigned short* sml = smem + 16384;

  const int tid = threadIdx.x;
  const int lane = tid & 63;
  const int wv = tid >> 6;
  const long row0 = ((long)blockIdx.x * 8 + wv) * 16;
  const bool active = row0 < nrows;
  const int kgrp = (lane >> 4) * 8;
  const int r16 = lane & 15;
  const int cq = (lane >> 4) * 4;
  unsigned short* tw = smem + wv * 4096;  // wave tile: hi[2048] | lo[2048]

  long rr = row0 + r16;
  const long arow = (rr < nrows) ? rr : (long)(nrows - 1);
  const long row = row0 + r16;

#pragma unroll
  for (int k = 0; k < 4; ++k) {
    int t = tid + k * 512;
    gload_lds16((const uint4*)W1h + t, (uint4*)smh + t);
    gload_lds16((const uint4*)W1l + t, (uint4*)sml + t);
  }
  bf16x8 a_h[4], a_l[4];
  if (active) {
#pragma unroll
    for (int ks = 0; ks < 4; ++ks) {
      a_h[ks] = *(const bf16x8*)(X + arow * 256 + ks * 32 + kgrp);
      a_l[ks] = *(const bf16x8*)(X + arow * 256 + 128 + ks * 32 + kgrp);
    }
  }
  f32x4 zero = {0.f, 0.f, 0.f, 0.f};
  f32x4 acc[8];
#pragma unroll
  for (int t = 0; t < 8; ++t) acc[t] = zero;

  __syncthreads();  // pW1 staged
  if (active) mm3term(acc, a_h, a_l, smh, sml, lane);  // h1 pre-act
  __syncthreads();  // pW1 region free

  if (active) {
    t_store<true>(acc, b1, tw, r16, cq);   // h1 = relu(.+b1) -> tile
    t_load(a_h, a_l, tw, r16, kgrp);       // h1 frags
  }
  __syncthreads();  // tiles free

#pragma unroll
  for (int k = 0; k < 4; ++k) {
    int t = tid + k * 512;
    gload_lds16((const uint4*)W2h + t, (uint4*)smh + t);
    gload_lds16((const uint4*)W2l + t, (uint4*)sml + t);
  }
#pragma unroll
  for (int t = 0; t < 8; ++t) acc[t] = zero;
  __syncthreads();  // pW2 staged
  if (active) mm3term(acc, a_h, a_l, smh, sml, lane);  // x2 pre-act
  __syncthreads();  // pW2 region free

  if (active) {
    t_store<false>(acc, b2, tw, r16, cq);  // x2 = . + b2 -> tile
    t_load(a_h, a_l, tw, r16, kgrp);       // x2 frags (persist for u AND v)
  }
  __syncthreads();  // tiles free

#pragma unroll
  for (int k = 0; k < 4; ++k) {
    int t = tid + k * 512;
    gload_lds16((const uint4*)W3h + t, (uint4*)smh + t);
    gload_lds16((const uint4*)W3l + t, (uint4*)sml + t);
  }
#pragma unroll
  for (int t = 0; t < 8; ++t) acc[t] = zero;
  __syncthreads();  // qW1t staged
  if (active) mm3term(acc, a_h, a_l, smh, sml, lane);  // u pre-bias
  if (active && row < nrows) {
#pragma unroll
    for (int nt = 0; nt < 8; ++nt) {
      const int col = nt * 16 + cq;
      float4 bv = *(const float4*)(b3 + col);
      unsigned short h0 = f2bf(acc[nt][0] + bv.x), h1 = f2bf(acc[nt][1] + bv.y);
      unsigned short h2 = f2bf(acc[nt][2] + bv.z), h3 = f2bf(acc[nt][3] + bv.w);
      uint2 oh;
      oh.x = (unsigned)h0 | ((unsigned)h1 << 16);
      oh.y = (unsigned)h2 | ((unsigned)h3 << 16);
      *(uint2*)(U + row * 128 + col) = oh;
    }
  }
  __syncthreads();  // qW1t region free

#pragma unroll
  for (int k = 0; k < 4; ++k) {
    int t = tid + k * 512;
    gload_lds16((const uint4*)W4h + t, (uint4*)smh + t);
    gload_lds16((const uint4*)W4l + t, (uint4*)sml + t);
  }
#pragma unroll
  for (int t = 0; t < 8; ++t) acc[t] = zero;
  __syncthreads();  // qW1b staged
  if (!active || row >= nrows) return;
  mm3term(acc, a_h, a_l, smh, sml, lane);  // v pre-bias
#pragma unroll
  for (int nt = 0; nt < 8; ++nt) {
    const int col = nt * 16 + cq;
    float4 bv = *(const float4*)(b4 + col);
    unsigned short h0 = f2bf(acc[nt][0] + bv.x), h1 = f2bf(acc[nt][1] + bv.y);
    unsigned short h2 = f2bf(acc[nt][2] + bv.z), h3 = f2bf(acc[nt][3] + bv.w);
    uint2 oh;
    oh.x = (unsigned)h0 | ((unsigned)h1 << 16);
    oh.y = (unsigned)h2 | ((unsigned)h3 << 16);
    *(uint2*)(V + row * 128 + col) = oh;
  }
}

// ---------------- predict pair: y = relu(u[i]+v[j]) . qW2 + qb2 -------------
__global__ __launch_bounds__(256) void k_pair(
    const unsigned short* __restrict__ u, const unsigned short* __restrict__ v,
    const int* __restrict__ ps, const int* __restrict__ pd,
    const float* __restrict__ qW2, const float* __restrict__ qb2,
    float* __restrict__ out, int EP) {
  int gid = blockIdx.x * blockDim.x + threadIdx.x;
  long wid = gid >> 6;
  int lane = gid & 63;
  int sub = lane & 15, g = lane >> 4;
  long base = wid * 8;
  if (base >= EP) return;
  float4 q0 = *(const float4*)(qW2 + sub * 8);
  float4 q1 = *(const float4*)(qW2 + sub * 8 + 4);
  float qb = qb2[0];

  long p0 = base + g;
  long p1 = base + 4 + g;
  long c0 = (p0 < EP) ? p0 : (EP - 1);
  long c1 = (p1 < EP) ? p1 : (EP - 1);
  int i0 = ps[c0], j0 = pd[c0];
  int i1 = ps[c1], j1 = pd[c1];
  uint4 a0 = *(const uint4*)(u + (size_t)i0 * 128 + sub * 8);
  uint4 b0 = *(const uint4*)(v + (size_t)j0 * 128 + sub * 8);
  uint4 a1 = *(const uint4*)(u + (size_t)i1 * 128 + sub * 8);
  uint4 b1 = *(const uint4*)(v + (size_t)j1 * 128 + sub * 8);

  float s0, s1;
  {
    float t;
    t = fmaxf(lo16f(a0.x) + lo16f(b0.x), 0.f) * q0.x;
    t = fmaf(fmaxf(hi16f(a0.x) + hi16f(b0.x), 0.f), q0.y, t);
    t = fmaf(fmaxf(lo16f(a0.y) + lo16f(b0.y), 0.f), q0.z, t);
    t = fmaf(fmaxf(hi16f(a0.y) + hi16f(b0.y), 0.f), q0.w, t);
    t = fmaf(fmaxf(lo16f(a0.z) + lo16f(b0.z), 0.f), q1.x, t);
    t = fmaf(fmaxf(hi16f(a0.z) + hi16f(b0.z), 0.f), q1.y, t);
    t = fmaf(fmaxf(lo16f(a0.w) + lo16f(b0.w), 0.f), q1.z, t);
    t = fmaf(fmaxf(hi16f(a0.w) + hi16f(b0.w), 0.f), q1.w, t);
    s0 = t;
    t = fmaxf(lo16f(a1.x) + lo16f(b1.x), 0.f) * q0.x;
    t = fmaf(fmaxf(hi16f(a1.x) + hi16f(b1.x), 0.f), q0.y, t);
    t = fmaf(fmaxf(lo16f(a1.y) + lo16f(b1.y), 0.f), q0.z, t);
    t = fmaf(fmaxf(hi16f(a1.y) + hi16f(b1.y), 0.f), q0.w, t);
    t = fmaf(fmaxf(lo16f(a1.z) + lo16f(b1.z), 0.f), q1.x, t);
    t = fmaf(fmaxf(hi16f(a1.z) + hi16f(b1.z), 0.f), q1.y, t);
    t = fmaf(fmaxf(lo16f(a1.w) + lo16f(b1.w), 0.f), q1.z, t);
    t = fmaf(fmaxf(hi16f(a1.w) + hi16f(b1.w), 0.f), q1.w, t);
    s1 = t;
  }
#pragma unroll
  for (int m = 1; m < 16; m <<= 1) {
    s0 += __shfl_xor(s0, m);
    s1 += __shfl_xor(s1, m);
  }
  if (sub == 0) {
    if (p0 < EP) out[p0] = s0 + qb;
    if (p1 < EP) out[p1] = s1 + qb;
  }
}

extern "C" void kernel_launch(void* const* d_in, const int* in_sizes, int n_in,
                              void* d_out, int out_size, void* d_ws, size_t ws_size,
                              hipStream_t stream) {
  const float* x_in = (const float*)d_in[0];
  // d_in[1] edge_attr: dead
  const int* ei = (const int*)d_in[2];
  const int* pe = (const int*)d_in[3];
  const float* Wl = (const float*)d_in[4];
  const float* bl = (const float*)d_in[5];
  const float* Wr = (const float*)d_in[6];
  // d_in[7..10] edge-update weights: dead
  const float* pW1 = (const float*)d_in[11];
  const float* pb1 = (const float*)d_in[12];
  const float* pW2 = (const float*)d_in[13];
  const float* pb2 = (const float*)d_in[14];
  const float* qW1 = (const float*)d_in[15];
  const float* qb1 = (const float*)d_in[16];
  const float* qW2 = (const float*)d_in[17];
  const float* qb2 = (const float*)d_in[18];

  const int N = in_sizes[0] / 128;
  const int E = in_sizes[2] / 2;
  const int EP = in_sizes[3] / 2;
  const int* e_src = ei;
  const int* e_dst = ei + E;
  const int* p_src = pe;
  const int* p_dst = pe + EP;

  char* ws = (char*)d_ws;
  size_t off = 0;
  auto alloc = [&](size_t bytes) {
    void* p = ws + off;
    off += (bytes + 511) & ~(size_t)511;
    return p;
  };
  // X0/X1: interleaved [node][hi|lo] ping-pong buffers (512 B rows)
  unsigned short* X0 = (unsigned short*)alloc((size_t)N * 256 * 2);  // 25.6 MB
  unsigned short* X1 = (unsigned short*)alloc((size_t)N * 256 * 2);  // 25.6 MB
  int* deg_i = (int*)alloc((size_t)N * 4);
  int* rs = (int*)alloc((size_t)(N + 1) * 4);
  int* cursor = (int*)alloc((size_t)N * 4);
  float* degf = (float*)alloc((size_t)N * 4);
  int* csr = (int*)alloc((size_t)E * 4);
  int* bsum = (int*)alloc(64 * 4);
  unsigned short* Whi = (unsigned short*)alloc((size_t)10 * 16384 * 2);
  unsigned short* Wlo = (unsigned short*)alloc((size_t)10 * 16384 * 2);
  float* zerob = (float*)alloc(128 * 4);

  const size_t MS = 16384;  // mat stride in ushorts
  const int nb = (N + 1023) / 1024;

  hipMemsetAsync(deg_i, 0, (size_t)N * 4, stream);
  hipMemsetAsync(zerob, 0, 128 * 4, stream);

  // pack all 10 weight mats (frag order, hi/lo split); mats 8,9 = qW1 t/b
  k_packAll<<<(10 * 2048 + 255) / 256, 256, 0, stream>>>(Wl, Wr, pW1, pW2, qW1,
                                                         Whi, Wlo);

  // x -> interleaved hi|lo (X0)
  long n2 = (long)N * 64;
  k_split<<<(int)((n2 + 255) / 256), 256, 0, stream>>>(x_in, (unsigned*)X0, n2);

  // CSR (hierarchical scan; block-sum scan folded into scan3)
  k_count<<<(E + 255) / 256, 256, 0, stream>>>(e_dst, deg_i, E);
  k_scan1<<<nb, 1024, 0, stream>>>(deg_i, rs, degf, bsum, N);
  k_scan3<<<(N + 255) / 256, 256, 0, stream>>>(rs, bsum, cursor, N, nb);
  k_scatter<<<(E + 255) / 256, 256, 0, stream>>>(e_src, e_dst, cursor, csr, E);

  const int gmm = (N + 127) / 128;  // 128 rows/block, 8 waves

  // fused layers, X ping-pong: X0 -> X1 -> X0 -> X1
  unsigned short* Xi = X0;
  unsigned short* Xo = X1;
  for (int l = 0; l < 3; ++l) {
    k_layer<<<gmm, 512, 0, stream>>>(
        Xi, csr, rs, degf, Whi + (size_t)l * MS, Wlo + (size_t)l * MS,
        Whi + (size_t)(3 + l) * MS, Wlo + (size_t)(3 + l) * MS,
        bl + (size_t)l * 128, Xo, N);
    unsigned short* t = Xi; Xi = Xo; Xo = t;
  }
  // after 3 layers: final features in Xi (= X1); Xo (= X0) is free -> u|v
  unsigned short* u = Xo;
  unsigned short* v = Xo + (size_t)N * 128;
  k_post<<<gmm, 512, 0, stream>>>(
      Xi, Whi + 6 * MS, Wlo + 6 * MS, Whi + 7 * MS, Wlo + 7 * MS,
      Whi + 8 * MS, Wlo + 8 * MS, Whi + 9 * MS, Wlo + 9 * MS,
      pb1, pb2, qb1, zerob, u, v, N);
  // y = relu(u[i]+v[j]) . qW2 + qb2
  k_pair<<<(EP + 31) / 32, 256, 0, stream>>>(u, v, p_src, p_dst, qW2, qb2,
                                             (float*)d_out, EP);
}

// Round 15
// 281.833 us; speedup vs baseline: 1.1356x; 1.0051x over previous
//
#include <hip/hip_runtime.h>

// ---------------------------------------------------------------------------
// GNNStack — dead-code-eliminated (edge-update MLPs never reach the output).
// Matmuls on MFMA bf16, split precision where it matters:
//   X (node features): interleaved [node][hi 128 | lo 128] bf16 (512 B row)
//   aggregated mean: bf16 hi only (inputs already bf16) — per round-10 A/B.
//   C = Ahi*Bhi (+ Alo*Bhi where A has lo) + Ahi*Blo, fp32 AGPR accum.
// k_layer FUSES mean-aggregation + 2-phase GEMM: each lane gathers its own
// row's neighbors over its own 32-dim slice (4 kgrp-lanes cover one 64B line
// per neighbor -> full coalescing), mean lands directly in the MFMA A-frag.
// X ping-pongs across layers (gather reads all rows; no in-place write).
// Post-pipeline h1->x2->u|v fused (k_post) with per-wave LDS transpose bounce.
// ---------------------------------------------------------------------------

typedef __attribute__((ext_vector_type(8))) short bf16x8;
typedef __attribute__((ext_vector_type(4))) float f32x4;

__device__ __forceinline__ unsigned short f2bf(float x) {
  unsigned u = __float_as_uint(x);
  u += 0x7fffu + ((u >> 16) & 1u);
  return (unsigned short)(u >> 16);
}
__device__ __forceinline__ float bf2f(unsigned short h) {
  return __uint_as_float(((unsigned)h) << 16);
}
__device__ __forceinline__ float lo16f(unsigned u) { return __uint_as_float(u << 16); }
__device__ __forceinline__ float hi16f(unsigned u) { return __uint_as_float(u & 0xffff0000u); }

// async global -> LDS, 16 bytes per lane (wave-uniform base + lane*16 pattern)
__device__ __forceinline__ void gload_lds16(const void* g, void* l) {
  __builtin_amdgcn_global_load_lds(
      (const __attribute__((address_space(1))) unsigned int*)g,
      (__attribute__((address_space(3))) unsigned int*)l, 16, 0, 0);
}

// ---------------- CSR build ----------------
__global__ void k_count(const int* __restrict__ dst, int* __restrict__ cnt, int E) {
  int i = blockIdx.x * blockDim.x + threadIdx.x;
  if (i < E) atomicAdd(&cnt[dst[i]], 1);
}

__global__ void k_scan1(const int* __restrict__ cnt, int* __restrict__ rs,
                        float* __restrict__ degf, int* __restrict__ bsum, int n) {
  __shared__ int wsum[16];
  __shared__ int wpre[16];
  const int tid = threadIdx.x;
  const int lane = tid & 63;
  const int wv = tid >> 6;
  int i = blockIdx.x * 1024 + tid;
  int v = (i < n) ? cnt[i] : 0;
  int s = v;
#pragma unroll
  for (int off = 1; off < 64; off <<= 1) {
    int t = __shfl_up(s, off);
    if (lane >= off) s += t;
  }
  if (lane == 63) wsum[wv] = s;
  __syncthreads();
  if (tid < 16) {
    int t = wsum[tid];
    int ss = t;
#pragma unroll
    for (int off = 1; off < 16; off <<= 1) {
      int u = __shfl_up(ss, off);
      if (tid >= off) ss += u;
    }
    wpre[tid] = ss - t;
  }
  __syncthreads();
  if (i < n) {
    rs[i] = s - v + wpre[wv];
    degf[i] = (float)(v > 0 ? v : 1);
  }
  if (tid == 1023) bsum[blockIdx.x] = wpre[15] + wsum[15];
}

// scan of block sums folded in: wave 0 of every block redundantly scans bsum
__global__ void k_scan3(int* __restrict__ rs, const int* __restrict__ bsum,
                        int* __restrict__ cursor, int n, int nb) {
  __shared__ int boff_s[64];
  __shared__ int total_s;
  int tid = threadIdx.x;
  if (tid < 64) {
    int v = (tid < nb) ? bsum[tid] : 0;
    int s = v;
#pragma unroll
    for (int off = 1; off < 64; off <<= 1) {
      int t = __shfl_up(s, off);
      if (tid >= off) s += t;
    }
    boff_s[tid] = s - v;
    if (tid == 63) total_s = s;
  }
  __syncthreads();
  int i = blockIdx.x * blockDim.x + tid;
  if (i < n) {
    int r = rs[i] + boff_s[i >> 10];
    rs[i] = r;
    cursor[i] = r;
  }
  if (blockIdx.x == 0 && tid == 0) rs[n] = total_s;
}

__global__ void k_scatter(const int* __restrict__ src, const int* __restrict__ dst,
                          int* __restrict__ cursor, int* __restrict__ csr, int E) {
  int i = blockIdx.x * blockDim.x + threadIdx.x;
  if (i < E) {
    int p = atomicAdd(&cursor[dst[i]], 1);
    csr[p] = src[i];
  }
}

// ---------------- fp32 -> interleaved hi|lo X row ----------------
__global__ void k_split(const float* __restrict__ x, unsigned* __restrict__ X,
                        long n2) {
  long g = (long)blockIdx.x * blockDim.x + threadIdx.x;
  if (g >= n2) return;
  float2 v = ((const float2*)x)[g];
  unsigned short hx = f2bf(v.x), hy = f2bf(v.y);
  unsigned short lx = f2bf(v.x - bf2f(hx)), ly = f2bf(v.y - bf2f(hy));
  long row = g >> 6, p = g & 63;
  X[row * 128 + p] = (unsigned)hx | ((unsigned)hy << 16);
  X[row * 128 + 64 + p] = (unsigned)lx | ((unsigned)ly << 16);
}

// ---------------- all weights pack: frag-order bf16 hi/lo, 10 mats ----------
// frag f = nt*4 + ks; lane l supplies B[k0 + 8*(l>>4) + r][nt*16 + (l&15)]
__global__ void k_packAll(const float* __restrict__ Wl, const float* __restrict__ Wr,
                          const float* __restrict__ pW1, const float* __restrict__ pW2,
                          const float* __restrict__ qW1,
                          unsigned short* __restrict__ hi,
                          unsigned short* __restrict__ lo) {
  int gid = blockIdx.x * blockDim.x + threadIdx.x;
  if (gid >= 10 * 2048) return;
  int mat = gid >> 11;
  const float* Wm;
  if (mat < 3) Wm = Wl + (size_t)mat * 16384;
  else if (mat < 6) Wm = Wr + (size_t)(mat - 3) * 16384;
  else if (mat == 6) Wm = pW1;
  else if (mat == 7) Wm = pW2;
  else Wm = qW1 + (size_t)(mat - 8) * 16384;
  int lane = gid & 63;
  int f = (gid >> 6) & 31;
  int nt = f >> 2, ks = f & 3;
  int nn = nt * 16 + (lane & 15);
  int k0 = ks * 32 + 8 * (lane >> 4);
  size_t dst = (size_t)gid * 8;
#pragma unroll
  for (int r = 0; r < 8; ++r) {
    float w = Wm[(size_t)(k0 + r) * 128 + nn];
    unsigned short h = f2bf(w);
    hi[dst + r] = h;
    lo[dst + r] = f2bf(w - bf2f(h));
  }
}

// ---------------- MFMA building blocks --------------------------------------
__device__ __forceinline__ void mm3term(f32x4 acc[8], const bf16x8 a_h[4],
                                        const bf16x8 a_l[4],
                                        const unsigned short* smh,
                                        const unsigned short* sml, int lane) {
#pragma unroll
  for (int ks = 0; ks < 4; ++ks)
#pragma unroll
    for (int nt = 0; nt < 8; ++nt) {
      const bf16x8 b_h = *(const bf16x8*)(smh + (nt * 4 + ks) * 512 + lane * 8);
      const bf16x8 b_l = *(const bf16x8*)(sml + (nt * 4 + ks) * 512 + lane * 8);
      acc[nt] = __builtin_amdgcn_mfma_f32_16x16x32_bf16(b_h, a_h[ks], acc[nt], 0, 0, 0);
      acc[nt] = __builtin_amdgcn_mfma_f32_16x16x32_bf16(b_h, a_l[ks], acc[nt], 0, 0, 0);
      acc[nt] = __builtin_amdgcn_mfma_f32_16x16x32_bf16(b_l, a_h[ks], acc[nt], 0, 0, 0);
    }
}

// acc(+bias,opt relu) -> per-wave 16x128 transpose tile (hi/lo planes, XOR swz)
template <bool RELU>
__device__ __forceinline__ void t_store(const f32x4 acc[8], const float* bias,
                                        unsigned short* tw, int r16, int cq) {
#pragma unroll
  for (int nt = 0; nt < 8; ++nt) {
    int col = nt * 16 + cq;
    float4 bv = *(const float4*)(bias + col);
    float v0 = acc[nt][0] + bv.x, v1 = acc[nt][1] + bv.y;
    float v2 = acc[nt][2] + bv.z, v3 = acc[nt][3] + bv.w;
    if (RELU) {
      v0 = fmaxf(v0, 0.f); v1 = fmaxf(v1, 0.f);
      v2 = fmaxf(v2, 0.f); v3 = fmaxf(v3, 0.f);
    }
    unsigned short h0 = f2bf(v0), h1 = f2bf(v1), h2 = f2bf(v2), h3 = f2bf(v3);
    uint2 oh, ol;
    oh.x = (unsigned)h0 | ((unsigned)h1 << 16);
    oh.y = (unsigned)h2 | ((unsigned)h3 << 16);
    ol.x = (unsigned)f2bf(v0 - bf2f(h0)) | ((unsigned)f2bf(v1 - bf2f(h1)) << 16);
    ol.y = (unsigned)f2bf(v2 - bf2f(h2)) | ((unsigned)f2bf(v3 - bf2f(h3)) << 16);
    int idx = (r16 * 128 + col) ^ ((r16 & 7) << 3);
    *(uint2*)(tw + idx) = oh;
    *(uint2*)(tw + 2048 + idx) = ol;
  }
}

__device__ __forceinline__ void t_load(bf16x8 a_h[4], bf16x8 a_l[4],
                                       const unsigned short* tw, int r16, int kgrp) {
#pragma unroll
  for (int ks = 0; ks < 4; ++ks) {
    int idx = (r16 * 128 + ks * 32 + kgrp) ^ ((r16 & 7) << 3);
    a_h[ks] = *(const bf16x8*)(tw + idx);
    a_l[ks] = *(const bf16x8*)(tw + 2048 + idx);
  }
}

// ---------------- fused layer: per-lane aggregation + 2-phase GEMM ----------
// x_out = relu(mean(Xin[nbrs]) @ Wl + Xin @ Wr + bl). Lane (r16,kgrp) gathers
// dims [ks*32+kgrp,+8) of row row0+r16's neighbors; 4 kgrp-lanes at the same
// neighbor cover one 64B line -> fully coalesced. Mean -> A-frag in regs.
__global__ __launch_bounds__(512, 4) void k_layer(
    const unsigned short* __restrict__ Xin,
    const int* __restrict__ csr, const int* __restrict__ rs,
    const float* __restrict__ degf,
    const unsigned short* __restrict__ W0h, const unsigned short* __restrict__ W0l,
    const unsigned short* __restrict__ W1h, const unsigned short* __restrict__ W1l,
    const float* __restrict__ bias, unsigned short* __restrict__ Xout, int nrows) {
  __shared__ unsigned short smem[32768];
  unsigned short* smh = smem;
  unsigned short* sml = smem + 16384;

  const int tid = threadIdx.x;
  const int lane = tid & 63;
  const int wv = tid >> 6;
  const long row0 = ((long)blockIdx.x * 8 + wv) * 16;
  const bool active = row0 < nrows;
  const int r16 = lane & 15;
  const int kgrp = (lane >> 4) * 8;
  long rr = row0 + r16;
  const long arow = (rr < nrows) ? rr : (long)(nrows - 1);

  // stage phase-0 weights (Wl) async
#pragma unroll
  for (int k = 0; k < 4; ++k) {
    int t = tid + k * 512;
    gload_lds16((const uint4*)W0h + t, (uint4*)smh + t);
    gload_lds16((const uint4*)W0l + t, (uint4*)sml + t);
  }

  // per-lane mean aggregation over own row's neighbors, own 32-dim slice
  float am[4][8];
#pragma unroll
  for (int ks = 0; ks < 4; ++ks)
#pragma unroll
    for (int d = 0; d < 8; ++d) am[ks][d] = 0.f;

  bf16x8 a0h[4];
  if (active) {
    int s = rs[arow], e = rs[arow + 1];
    int j = s;
    for (; j + 1 < e; j += 2) {
      int n0 = csr[j], n1 = csr[j + 1];
      const unsigned short* b0 = Xin + (size_t)n0 * 256 + kgrp;
      const unsigned short* b1 = Xin + (size_t)n1 * 256 + kgrp;
#pragma unroll
      for (int ks = 0; ks < 4; ++ks) {
        uint4 v0 = *(const uint4*)(b0 + ks * 32);
        uint4 v1 = *(const uint4*)(b1 + ks * 32);
        am[ks][0] += lo16f(v0.x) + lo16f(v1.x);
        am[ks][1] += hi16f(v0.x) + hi16f(v1.x);
        am[ks][2] += lo16f(v0.y) + lo16f(v1.y);
        am[ks][3] += hi16f(v0.y) + hi16f(v1.y);
        am[ks][4] += lo16f(v0.z) + lo16f(v1.z);
        am[ks][5] += hi16f(v0.z) + hi16f(v1.z);
        am[ks][6] += lo16f(v0.w) + lo16f(v1.w);
        am[ks][7] += hi16f(v0.w) + hi16f(v1.w);
      }
    }
    if (j < e) {
      int n0 = csr[j];
      const unsigned short* b0 = Xin + (size_t)n0 * 256 + kgrp;
#pragma unroll
      for (int ks = 0; ks < 4; ++ks) {
        uint4 v0 = *(const uint4*)(b0 + ks * 32);
        am[ks][0] += lo16f(v0.x); am[ks][1] += hi16f(v0.x);
        am[ks][2] += lo16f(v0.y); am[ks][3] += hi16f(v0.y);
        am[ks][4] += lo16f(v0.z); am[ks][5] += hi16f(v0.z);
        am[ks][6] += lo16f(v0.w); am[ks][7] += hi16f(v0.w);
      }
    }
    float inv = 1.0f / degf[arow];
#pragma unroll
    for (int ks = 0; ks < 4; ++ks) {
      uint4 p;
      p.x = (unsigned)f2bf(am[ks][0] * inv) | ((unsigned)f2bf(am[ks][1] * inv) << 16);
      p.y = (unsigned)f2bf(am[ks][2] * inv) | ((unsigned)f2bf(am[ks][3] * inv) << 16);
      p.z = (unsigned)f2bf(am[ks][4] * inv) | ((unsigned)f2bf(am[ks][5] * inv) << 16);
      p.w = (unsigned)f2bf(am[ks][6] * inv) | ((unsigned)f2bf(am[ks][7] * inv) << 16);
      union { uint4 u; bf16x8 b; } cvt;
      cvt.u = p;
      a0h[ks] = cvt.b;
    }
  }

  // phase-1 A frags from Xin (hi + lo)
  bf16x8 a1h[4], a1l[4];
  if (active) {
#pragma unroll
    for (int ks = 0; ks < 4; ++ks) {
      a1h[ks] = *(const bf16x8*)(Xin + arow * 256 + ks * 32 + kgrp);
      a1l[ks] = *(const bf16x8*)(Xin + arow * 256 + 128 + ks * 32 + kgrp);
    }
  }

  f32x4 zero = {0.f, 0.f, 0.f, 0.f};
  f32x4 acc[8];
#pragma unroll
  for (int t = 0; t < 8; ++t) acc[t] = zero;

  __syncthreads();  // Wl staged

  if (active) {
#pragma unroll
    for (int ks = 0; ks < 4; ++ks)
#pragma unroll
      for (int nt = 0; nt < 8; ++nt) {
        const bf16x8 b_h = *(const bf16x8*)(smh + (nt * 4 + ks) * 512 + lane * 8);
        const bf16x8 b_l = *(const bf16x8*)(sml + (nt * 4 + ks) * 512 + lane * 8);
        acc[nt] = __builtin_amdgcn_mfma_f32_16x16x32_bf16(b_h, a0h[ks], acc[nt], 0, 0, 0);
        acc[nt] = __builtin_amdgcn_mfma_f32_16x16x32_bf16(b_l, a0h[ks], acc[nt], 0, 0, 0);
      }
  }

  __syncthreads();  // Wl region free
#pragma unroll
  for (int k = 0; k < 4; ++k) {
    int t = tid + k * 512;
    gload_lds16((const uint4*)W1h + t, (uint4*)smh + t);
    gload_lds16((const uint4*)W1l + t, (uint4*)sml + t);
  }
  __syncthreads();  // Wr staged
  if (!active) return;

  mm3term(acc, a1h, a1l, smh, sml, lane);

  const int cq = (lane >> 4) * 4;
  const long row = row0 + r16;
  if (row >= nrows) return;
#pragma unroll
  for (int nt = 0; nt < 8; ++nt) {
    const int col = nt * 16 + cq;
    float4 bv = *(const float4*)(bias + col);
    float v0 = fmaxf(acc[nt][0] + bv.x, 0.f);
    float v1 = fmaxf(acc[nt][1] + bv.y, 0.f);
    float v2 = fmaxf(acc[nt][2] + bv.z, 0.f);
    float v3 = fmaxf(acc[nt][3] + bv.w, 0.f);
    unsigned short h0 = f2bf(v0), h1 = f2bf(v1), h2 = f2bf(v2), h3 = f2bf(v3);
    uint2 oh, ol;
    oh.x = (unsigned)h0 | ((unsigned)h1 << 16);
    oh.y = (unsigned)h2 | ((unsigned)h3 << 16);
    ol.x = (unsigned)f2bf(v0 - bf2f(h0)) | ((unsigned)f2bf(v1 - bf2f(h1)) << 16);
    ol.y = (unsigned)f2bf(v2 - bf2f(h2)) | ((unsigned)f2bf(v3 - bf2f(h3)) << 16);
    *(uint2*)(Xout + row * 256 + col) = oh;
    *(uint2*)(Xout + row * 256 + 128 + col) = ol;
  }
}

// ---------------- fused post pipeline: h1 -> x2 -> u|v ----------------------
__global__ __launch_bounds__(512, 2) void k_post(
    const unsigned short* __restrict__ X,
    const unsigned short* __restrict__ W1h, const unsigned short* __restrict__ W1l,
    const unsigned short* __restrict__ W2h, const unsigned short* __restrict__ W2l,
    const unsigned short* __restrict__ W3h, const unsigned short* __restrict__ W3l,
    const unsigned short* __restrict__ W4h, const unsigned short* __restrict__ W4l,
    const float* __restrict__ b1, const float* __restrict__ b2,
    const float* __restrict__ b3, const float* __restrict__ b4,
    unsigned short* __restrict__ U, unsigned short* __restrict__ V, int nrows) {
  __shared__ unsigned short smem[32768];  // weights OR 8x per-wave 16x128 tiles
  unsigned short* smh = smem;
  unsigned short* sml = smem + 16384;

  const int tid = threadIdx.x;
  const int lane = tid & 63;
  const int wv = tid >> 6;
  const long row0 = ((long)blockIdx.x * 8 + wv) * 16;
  const bool active = row0 < nrows;
  const int kgrp = (lane >> 4) * 8;
  const int r16 = lane & 15;
  const int cq = (lane >> 4) * 4;
  unsigned short* tw = smem + wv * 4096;  // wave tile: hi[2048] | lo[2048]

  long rr = row0 + r16;
  const long arow = (rr < nrows) ? rr : (long)(nrows - 1);
  const long row = row0 + r16;

#pragma unroll
  for (int k = 0; k < 4; ++k) {
    int t = tid + k * 512;
    gload_lds16((const uint4*)W1h + t, (uint4*)smh + t);
    gload_lds16((const uint4*)W1l + t, (uint4*)sml + t);
  }
  bf16x8 a_h[4], a_l[4];
  if (active) {
#pragma unroll
    for (int ks = 0; ks < 4; ++ks) {
      a_h[ks] = *(const bf16x8*)(X + arow * 256 + ks * 32 + kgrp);
      a_l[ks] = *(const bf16x8*)(X + arow * 256 + 128 + ks * 32 + kgrp);
    }
  }
  f32x4 zero = {0.f, 0.f, 0.f, 0.f};
  f32x4 acc[8];
#pragma unroll
  for (int t = 0; t < 8; ++t) acc[t] = zero;

  __syncthreads();  // pW1 staged
  if (active) mm3term(acc, a_h, a_l, smh, sml, lane);  // h1 pre-act
  __syncthreads();  // pW1 region free

  if (active) {
    t_store<true>(acc, b1, tw, r16, cq);   // h1 = relu(.+b1) -> tile
    t_load(a_h, a_l, tw, r16, kgrp);       // h1 frags
  }
  __syncthreads();  // tiles free

#pragma unroll
  for (int k = 0; k < 4; ++k) {
    int t = tid + k * 512;
    gload_lds16((const uint4*)W2h + t, (uint4*)smh + t);
    gload_lds16((const uint4*)W2l + t, (uint4*)sml + t);
  }
#pragma unroll
  for (int t = 0; t < 8; ++t) acc[t] = zero;
  __syncthreads();  // pW2 staged
  if (active) mm3term(acc, a_h, a_l, smh, sml, lane);  // x2 pre-act
  __syncthreads();  // pW2 region free

  if (active) {
    t_store<false>(acc, b2, tw, r16, cq);  // x2 = . + b2 -> tile
    t_load(a_h, a_l, tw, r16, kgrp);       // x2 frags (persist for u AND v)
  }
  __syncthreads();  // tiles free

#pragma unroll
  for (int k = 0; k < 4; ++k) {
    int t = tid + k * 512;
    gload_lds16((const uint4*)W3h + t, (uint4*)smh + t);
    gload_lds16((const uint4*)W3l + t, (uint4*)sml + t);
  }
#pragma unroll
  for (int t = 0; t < 8; ++t) acc[t] = zero;
  __syncthreads();  // qW1t staged
  if (active) mm3term(acc, a_h, a_l, smh, sml, lane);  // u pre-bias
  if (active && row < nrows) {
#pragma unroll
    for (int nt = 0; nt < 8; ++nt) {
      const int col = nt * 16 + cq;
      float4 bv = *(const float4*)(b3 + col);
      unsigned short h0 = f2bf(acc[nt][0] + bv.x), h1 = f2bf(acc[nt][1] + bv.y);
      unsigned short h2 = f2bf(acc[nt][2] + bv.z), h3 = f2bf(acc[nt][3] + bv.w);
      uint2 oh;
      oh.x = (unsigned)h0 | ((unsigned)h1 << 16);
      oh.y = (unsigned)h2 | ((unsigned)h3 << 16);
      *(uint2*)(U + row * 128 + col) = oh;
    }
  }
  __syncthreads();  // qW1t region free

#pragma unroll
  for (int k = 0; k < 4; ++k) {
    int t = tid + k * 512;
    gload_lds16((const uint4*)W4h + t, (uint4*)smh + t);
    gload_lds16((const uint4*)W4l + t, (uint4*)sml + t);
  }
#pragma unroll
  for (int t = 0; t < 8; ++t) acc[t] = zero;
  __syncthreads();  // qW1b staged
  if (!active || row >= nrows) return;
  mm3term(acc, a_h, a_l, smh, sml, lane);  // v pre-bias
#pragma unroll
  for (int nt = 0; nt < 8; ++nt) {
    const int col = nt * 16 + cq;
    float4 bv = *(const float4*)(b4 + col);
    unsigned short h0 = f2bf(acc[nt][0] + bv.x), h1 = f2bf(acc[nt][1] + bv.y);
    unsigned short h2 = f2bf(acc[nt][2] + bv.z), h3 = f2bf(acc[nt][3] + bv.w);
    uint2 oh;
    oh.x = (unsigned)h0 | ((unsigned)h1 << 16);
    oh.y = (unsigned)h2 | ((unsigned)h3 << 16);
    *(uint2*)(V + row * 128 + col) = oh;
  }
}

// ---------------- predict pair: y = relu(u[i]+v[j]) . qW2 + qb2 -------------
__global__ __launch_bounds__(256) void k_pair(
    const unsigned short* __restrict__ u, const unsigned short* __restrict__ v,
    const int* __restrict__ ps, const int* __restrict__ pd,
    const float* __restrict__ qW2, const float* __restrict__ qb2,
    float* __restrict__ out, int EP) {
  int gid = blockIdx.x * blockDim.x + threadIdx.x;
  long wid = gid >> 6;
  int lane = gid & 63;
  int sub = lane & 15, g = lane >> 4;
  long base = wid * 8;
  if (base >= EP) return;
  float4 q0 = *(const float4*)(qW2 + sub * 8);
  float4 q1 = *(const float4*)(qW2 + sub * 8 + 4);
  float qb = qb2[0];

  long p0 = base + g;
  long p1 = base + 4 + g;
  long c0 = (p0 < EP) ? p0 : (EP - 1);
  long c1 = (p1 < EP) ? p1 : (EP - 1);
  int i0 = ps[c0], j0 = pd[c0];
  int i1 = ps[c1], j1 = pd[c1];
  uint4 a0 = *(const uint4*)(u + (size_t)i0 * 128 + sub * 8);
  uint4 b0 = *(const uint4*)(v + (size_t)j0 * 128 + sub * 8);
  uint4 a1 = *(const uint4*)(u + (size_t)i1 * 128 + sub * 8);
  uint4 b1 = *(const uint4*)(v + (size_t)j1 * 128 + sub * 8);

  float s0, s1;
  {
    float t;
    t = fmaxf(lo16f(a0.x) + lo16f(b0.x), 0.f) * q0.x;
    t = fmaf(fmaxf(hi16f(a0.x) + hi16f(b0.x), 0.f), q0.y, t);
    t = fmaf(fmaxf(lo16f(a0.y) + lo16f(b0.y), 0.f), q0.z, t);
    t = fmaf(fmaxf(hi16f(a0.y) + hi16f(b0.y), 0.f), q0.w, t);
    t = fmaf(fmaxf(lo16f(a0.z) + lo16f(b0.z), 0.f), q1.x, t);
    t = fmaf(fmaxf(hi16f(a0.z) + hi16f(b0.z), 0.f), q1.y, t);
    t = fmaf(fmaxf(lo16f(a0.w) + lo16f(b0.w), 0.f), q1.z, t);
    t = fmaf(fmaxf(hi16f(a0.w) + hi16f(b0.w), 0.f), q1.w, t);
    s0 = t;
    t = fmaxf(lo16f(a1.x) + lo16f(b1.x), 0.f) * q0.x;
    t = fmaf(fmaxf(hi16f(a1.x) + hi16f(b1.x), 0.f), q0.y, t);
    t = fmaf(fmaxf(lo16f(a1.y) + lo16f(b1.y), 0.f), q0.z, t);
    t = fmaf(fmaxf(hi16f(a1.y) + hi16f(b1.y), 0.f), q0.w, t);
    t = fmaf(fmaxf(lo16f(a1.z) + lo16f(b1.z), 0.f), q1.x, t);
    t = fmaf(fmaxf(hi16f(a1.z) + hi16f(b1.z), 0.f), q1.y, t);
    t = fmaf(fmaxf(lo16f(a1.w) + lo16f(b1.w), 0.f), q1.z, t);
    t = fmaf(fmaxf(hi16f(a1.w) + hi16f(b1.w), 0.f), q1.w, t);
    s1 = t;
  }
#pragma unroll
  for (int m = 1; m < 16; m <<= 1) {
    s0 += __shfl_xor(s0, m);
    s1 += __shfl_xor(s1, m);
  }
  if (sub == 0) {
    if (p0 < EP) out[p0] = s0 + qb;
    if (p1 < EP) out[p1] = s1 + qb;
  }
}

extern "C" void kernel_launch(void* const* d_in, const int* in_sizes, int n_in,
                              void* d_out, int out_size, void* d_ws, size_t ws_size,
                              hipStream_t stream) {
  const float* x_in = (const float*)d_in[0];
  // d_in[1] edge_attr: dead
  const int* ei = (const int*)d_in[2];
  const int* pe = (const int*)d_in[3];
  const float* Wl = (const float*)d_in[4];
  const float* bl = (const float*)d_in[5];
  const float* Wr = (const float*)d_in[6];
  // d_in[7..10] edge-update weights: dead
  const float* pW1 = (const float*)d_in[11];
  const float* pb1 = (const float*)d_in[12];
  const float* pW2 = (const float*)d_in[13];
  const float* pb2 = (const float*)d_in[14];
  const float* qW1 = (const float*)d_in[15];
  const float* qb1 = (const float*)d_in[16];
  const float* qW2 = (const float*)d_in[17];
  const float* qb2 = (const float*)d_in[18];

  const int N = in_sizes[0] / 128;
  const int E = in_sizes[2] / 2;
  const int EP = in_sizes[3] / 2;
  const int* e_src = ei;
  const int* e_dst = ei + E;
  const int* p_src = pe;
  const int* p_dst = pe + EP;

  char* ws = (char*)d_ws;
  size_t off = 0;
  auto alloc = [&](size_t bytes) {
    void* p = ws + off;
    off += (bytes + 511) & ~(size_t)511;
    return p;
  };
  // X0/X1: interleaved [node][hi|lo] ping-pong buffers (512 B rows)
  unsigned short* X0 = (unsigned short*)alloc((size_t)N * 256 * 2);  // 25.6 MB
  unsigned short* X1 = (unsigned short*)alloc((size_t)N * 256 * 2);  // 25.6 MB
  int* deg_i = (int*)alloc((size_t)N * 4);
  int* rs = (int*)alloc((size_t)(N + 1) * 4);
  int* cursor = (int*)alloc((size_t)N * 4);
  float* degf = (float*)alloc((size_t)N * 4);
  int* csr = (int*)alloc((size_t)E * 4);
  int* bsum = (int*)alloc(64 * 4);
  unsigned short* Whi = (unsigned short*)alloc((size_t)10 * 16384 * 2);
  unsigned short* Wlo = (unsigned short*)alloc((size_t)10 * 16384 * 2);
  float* zerob = (float*)alloc(128 * 4);

  const size_t MS = 16384;  // mat stride in ushorts
  const int nb = (N + 1023) / 1024;

  hipMemsetAsync(deg_i, 0, (size_t)N * 4, stream);
  hipMemsetAsync(zerob, 0, 128 * 4, stream);

  // pack all 10 weight mats (frag order, hi/lo split); mats 8,9 = qW1 t/b
  k_packAll<<<(10 * 2048 + 255) / 256, 256, 0, stream>>>(Wl, Wr, pW1, pW2, qW1,
                                                         Whi, Wlo);

  // x -> interleaved hi|lo (X0)
  long n2 = (long)N * 64;
  k_split<<<(int)((n2 + 255) / 256), 256, 0, stream>>>(x_in, (unsigned*)X0, n2);

  // CSR (hierarchical scan; block-sum scan folded into scan3)
  k_count<<<(E + 255) / 256, 256, 0, stream>>>(e_dst, deg_i, E);
  k_scan1<<<nb, 1024, 0, stream>>>(deg_i, rs, degf, bsum, N);
  k_scan3<<<(N + 255) / 256, 256, 0, stream>>>(rs, bsum, cursor, N, nb);
  k_scatter<<<(E + 255) / 256, 256, 0, stream>>>(e_src, e_dst, cursor, csr, E);

  const int gmm = (N + 127) / 128;  // 128 rows/block, 8 waves

  // fused layers, X ping-pong: X0 -> X1 -> X0 -> X1
  unsigned short* Xi = X0;
  unsigned short* Xo = X1;
  for (int l = 0; l < 3; ++l) {
    k_layer<<<gmm, 512, 0, stream>>>(
        Xi, csr, rs, degf, Whi + (size_t)l * MS, Wlo + (size_t)l * MS,
        Whi + (size_t)(3 + l) * MS, Wlo + (size_t)(3 + l) * MS,
        bl + (size_t)l * 128, Xo, N);
    unsigned short* t = Xi; Xi = Xo; Xo = t;
  }
  // after 3 layers: final features in Xi (= X1); Xo (= X0) is free -> u|v
  unsigned short* u = Xo;
  unsigned short* v = Xo + (size_t)N * 128;
  k_post<<<gmm, 512, 0, stream>>>(
      Xi, Whi + 6 * MS, Wlo + 6 * MS, Whi + 7 * MS, Wlo + 7 * MS,
      Whi + 8 * MS, Wlo + 8 * MS, Whi + 9 * MS, Wlo + 9 * MS,
      pb1, pb2, qb1, zerob, u, v, N);
  // y = relu(u[i]+v[j]) . qW2 + qb2
  k_pair<<<(EP + 31) / 32, 256, 0, stream>>>(u, v, p_src, p_dst, qW2, qb2,
                                             (float*)d_out, EP);
}